// Round 7
// baseline (606.174 us; speedup 1.0000x reference)
//
#include <hip/hip_runtime.h>
#include <hip/hip_cooperative_groups.h>
#include <math.h>

namespace cg = cooperative_groups;

// B=256, D=256, H=8, HD=32, FF=1024, M=2048
#define SCALE_F 0.17677669529663687f

typedef __attribute__((ext_vector_type(8))) short short8;
typedef __attribute__((ext_vector_type(4))) float f32x4;

__device__ inline short tobf(float x) {
    unsigned u = __float_as_uint(x);
    unsigned r = (u + 0x7FFFu + ((u >> 16) & 1u)) >> 16;
    return (short)r;
}
__device__ inline float frombf(short s) {
    return __uint_as_float(((unsigned)(unsigned short)s) << 16);
}

struct KParams {
    const float *src, *memory, *momentum, *scores, *ipw, *ipb, *out_w, *out_b,
                *w1, *b1, *w2, *b2, *g1, *be1, *g2, *be2;
    const int* ptr;
    float *out_main, *mem_o, *mom_o, *sc_o;
    short *srcsplit, *memsplit, *ipw_bf, *outw_bf, *w1_bf, *w2_bf,
          *qkv_bf, *k_bf, *vt_bf, *ctx_bf, *hbuf_bf, *ff1_bf;
    float *simdot, *pvpart, *mpart, *lpart, *attn_part, *ff2_part, *hbuf,
          *nx, *nm, *nm2, *sur;
    int* inv;
};

// ---------- phase 0: convert + split packs + row norms ----------
__device__ __forceinline__ void cvt_job(const KParams& p, short* smem, int job) {
    int t = threadIdx.x;
    float* red = (float*)smem;
    if (job < 2304) {
        bool issrc = job < 256;
        int r = issrc ? job : job - 256;
        float x = issrc ? p.src[r * 256 + t] : p.memory[r * 256 + t];
        short hi = tobf(x); short lo = tobf(x - frombf(hi));
        long long b = (long long)r * 768;
        if (issrc) { p.srcsplit[b + t] = hi; p.srcsplit[b + 256 + t] = hi; p.srcsplit[b + 512 + t] = lo; }
        else       { p.memsplit[b + t] = hi; p.memsplit[b + 256 + t] = lo; p.memsplit[b + 512 + t] = hi; }
        red[t] = x * x; __syncthreads();
        for (int s = 128; s; s >>= 1) { if (t < s) red[t] += red[t + s]; __syncthreads(); }
        if (t == 0) {
            if (issrc) p.nx[r] = fmaxf(sqrtf(red[0]), 1e-8f);
            else { p.nm[r] = fmaxf(sqrtf(red[0]), 1e-8f); p.nm2[r] = red[0]; }
        }
        __syncthreads();
    } else {
        int i = job * 256 + t;
        int j = i - 589824;
        if (i < 786432)       p.ipw_bf[j] = tobf(p.ipw[j]);
        else if (i < 851968)  p.outw_bf[j - 196608] = tobf(p.out_w[j - 196608]);
        else if (i < 1114112) p.w1_bf[j - 262144] = tobf(p.w1[j - 262144]);
        else                  p.w2_bf[j - 524288] = tobf(p.w2[j - 524288]);
    }
}

// ---------- shared tile GEMM body: C[M,N] = alpha*A[M,K]@B[N,K]^T ----------
__device__ __forceinline__ void gemm_tile(short* lds,
    const short* __restrict__ A, int lda, const short* __restrict__ B, int ldb,
    float* Cf, short* Cb, int ldc, long long coff, const float* bias,
    int M, int N, int Klen, int kbeg, float alpha, int relu, int transC, int bx, int by)
{
    short* Al = lds;           // [64][40]
    short* Bl = lds + 2560;    // [64][40]
    int t = threadIdx.x, w = t >> 6, l = t & 63;
    int r0 = by * 64, c0 = bx * 64;
    int srow = t >> 2, scol = (t & 3) * 8;
    f32x4 acc[4] = {{0.f,0.f,0.f,0.f},{0.f,0.f,0.f,0.f},{0.f,0.f,0.f,0.f},{0.f,0.f,0.f,0.f}};
    for (int kk = 0; kk < Klen; kk += 32) {
        int k0 = kbeg + kk;
        short8 va = {0,0,0,0,0,0,0,0};
        if (r0 + srow < M) va = *(const short8*)(A + (long long)(r0 + srow) * lda + k0 + scol);
        *(short8*)&Al[srow * 40 + scol] = va;
        short8 vb = {0,0,0,0,0,0,0,0};
        if (c0 + srow < N) vb = *(const short8*)(B + (long long)(c0 + srow) * ldb + k0 + scol);
        *(short8*)&Bl[srow * 40 + scol] = vb;
        __syncthreads();
        short8 af = *(const short8*)&Al[(w * 16 + (l & 15)) * 40 + (l >> 4) * 8];
        #pragma unroll
        for (int j = 0; j < 4; j++) {
            short8 bf = *(const short8*)&Bl[(j * 16 + (l & 15)) * 40 + (l >> 4) * 8];
            acc[j] = __builtin_amdgcn_mfma_f32_16x16x32_bf16(af, bf, acc[j], 0, 0, 0);
        }
        __syncthreads();
    }
    int lc = l & 15, lr = (l >> 4) * 4;
    #pragma unroll
    for (int j = 0; j < 4; j++) {
        int col = c0 + j * 16 + lc;
        if (col >= N) continue;
        float bv = bias ? bias[col] : 0.f;
        #pragma unroll
        for (int r = 0; r < 4; r++) {
            int row = r0 + w * 16 + lr + r;
            if (row >= M) continue;
            float v = acc[j][r] * alpha + bv;
            if (relu) v = fmaxf(v, 0.f);
            long long idx = coff + (transC ? (long long)col * ldc + row
                                           : (long long)row * ldc + col);
            if (Cf) Cf[idx] = v;
            else    Cb[idx] = tobf(v);
        }
    }
}

// ---------- phase 1: grouped projections ----------
__device__ __forceinline__ void gemm4_job(const KParams& p, short* smem, int bid) {
    const short *A, *B; const float *bias; float *Cf; short *Cb;
    int lda, ldb, ldc, M, N, K, transC, bx, by;
    if (bid < 128) {            // simdot = srcsplit @ memsplit^T (K=768 split trick)
        A = p.srcsplit; lda = 768; B = p.memsplit; ldb = 768;
        Cf = p.simdot; Cb = nullptr; ldc = 2048; bias = nullptr;
        M = 256; N = 2048; K = 768; transC = 0;
        bx = bid & 31; by = bid >> 5;
    } else if (bid < 256) {     // k_bf = mem_hi @ Wk^T + bk
        int r = bid - 128;
        A = p.memsplit + 512; lda = 768; B = p.ipw_bf + 65536; ldb = 256;
        Cf = nullptr; Cb = p.k_bf; ldc = 256; bias = p.ipb + 256;
        M = 2048; N = 256; K = 256; transC = 0;
        bx = r & 3; by = r >> 2;
    } else if (bid < 384) {     // vt_bf = (mem_hi @ Wv^T + bv)^T
        int r = bid - 256;
        A = p.memsplit + 512; lda = 768; B = p.ipw_bf + 131072; ldb = 256;
        Cf = nullptr; Cb = p.vt_bf; ldc = 2048; bias = p.ipb + 512;
        M = 2048; N = 256; K = 256; transC = 1;
        bx = r & 3; by = r >> 2;
    } else {                    // qkv_bf = src_hi @ ipw^T + ipb
        int r = bid - 384;
        A = p.srcsplit; lda = 768; B = p.ipw_bf; ldb = 256;
        Cf = nullptr; Cb = p.qkv_bf; ldc = 768; bias = p.ipb;
        M = 256; N = 768; K = 256; transC = 0;
        bx = r % 12; by = r / 12;
    }
    gemm_tile(smem, A, lda, B, ldb, Cf, Cb, ldc, 0, bias, M, N, K, 0, 1.f, 0, transC, bx, by);
}

// ---------- phase 2a: flash attention (split-m) ----------
__device__ __forceinline__ void flash_job(const KParams& p, short* smem, int bid) {
    int ms = bid & 7, h = (bid >> 3) & 7, qt = bid >> 6;
    int q0 = qt * 64, m0 = ms * 256;
    int S = bid & 63;
    int t = threadIdx.x, w = t >> 6, l = t & 63;
    short* Ql = smem;            // [64][40]
    short* Kl = smem + 2560;     // [256][40]
    short* Pl = smem + 12800;    // [64][264]
    { int srow = t >> 2, scol = (t & 3) * 8;
      *(short8*)&Ql[srow * 40 + scol] = *(const short8*)(p.qkv_bf + (q0 + srow) * 768 + h * 32 + scol); }
    #pragma unroll
    for (int s = 0; s < 4; s++) {
        int seg = t + s * 256; int row = seg >> 2, off = (seg & 3) * 8;
        *(short8*)&Kl[row * 40 + off] = *(const short8*)(p.k_bf + (long long)(m0 + row) * 256 + h * 32 + off);
    }
    __syncthreads();
    short8 af = *(const short8*)&Ql[(w * 16 + (l & 15)) * 40 + (l >> 4) * 8];
    f32x4 accL[16];
    #pragma unroll
    for (int j = 0; j < 16; j++) accL[j] = f32x4{0.f, 0.f, 0.f, 0.f};
    #pragma unroll
    for (int j = 0; j < 16; j++) {
        short8 bf = *(const short8*)&Kl[(j * 16 + (l & 15)) * 40 + (l >> 4) * 8];
        accL[j] = __builtin_amdgcn_mfma_f32_16x16x32_bf16(af, bf, accL[j], 0, 0, 0);
    }
    int r4 = (l >> 4) * 4;
    float mloc[4], lsum[4];
    #pragma unroll
    for (int r = 0; r < 4; r++) {
        float mx = -1e30f;
        #pragma unroll
        for (int j = 0; j < 16; j++) mx = fmaxf(mx, accL[j][r] * SCALE_F);
        #pragma unroll
        for (int msk = 1; msk < 16; msk <<= 1) mx = fmaxf(mx, __shfl_xor(mx, msk, 64));
        mloc[r] = mx;
    }
    #pragma unroll
    for (int j = 0; j < 16; j++)
        #pragma unroll
        for (int r = 0; r < 4; r++)
            accL[j][r] = __expf(accL[j][r] * SCALE_F - mloc[r]);
    #pragma unroll
    for (int r = 0; r < 4; r++) {
        float ls = 0.f;
        #pragma unroll
        for (int j = 0; j < 16; j++) ls += accL[j][r];
        #pragma unroll
        for (int msk = 1; msk < 16; msk <<= 1) ls += __shfl_xor(ls, msk, 64);
        lsum[r] = ls;
    }
    if ((l & 15) == 0) {
        #pragma unroll
        for (int r = 0; r < 4; r++) {
            int gq = q0 + w * 16 + r4 + r;
            p.mpart[S * 256 + gq] = mloc[r];
            p.lpart[S * 256 + gq] = lsum[r];
        }
    }
    #pragma unroll
    for (int j = 0; j < 16; j++)
        #pragma unroll
        for (int r = 0; r < 4; r++)
            Pl[(w * 16 + r4 + r) * 264 + j * 16 + (l & 15)] = tobf(accL[j][r]);
    __syncthreads();
    f32x4 accP[2] = {{0.f,0.f,0.f,0.f},{0.f,0.f,0.f,0.f}};
    #pragma unroll
    for (int ks = 0; ks < 8; ks++) {
        short8 pa = *(const short8*)&Pl[(w * 16 + (l & 15)) * 264 + ks * 32 + (l >> 4) * 8];
        #pragma unroll
        for (int df = 0; df < 2; df++) {
            short8 vb = *(const short8*)(p.vt_bf + (long long)(h * 32 + df * 16 + (l & 15)) * 2048
                                         + m0 + ks * 32 + (l >> 4) * 8);
            accP[df] = __builtin_amdgcn_mfma_f32_16x16x32_bf16(pa, vb, accP[df], 0, 0, 0);
        }
    }
    #pragma unroll
    for (int df = 0; df < 2; df++)
        #pragma unroll
        for (int r = 0; r < 4; r++) {
            int gq = q0 + w * 16 + r4 + r;
            p.pvpart[((long long)S * 256 + gq) * 32 + df * 16 + (l & 15)] = accP[df][r];
        }
    __syncthreads();
}

// ---------- phase 2b: surprise ----------
__device__ __forceinline__ void surprise_job(const KParams& p, short* smem, int b) {
    float* red = (float*)smem;
    int t = threadIdx.x;
    float tot = 0.f;
    for (int m = t; m < 2048; m += 256) tot += p.nm2[m];
    red[t] = tot; __syncthreads();
    for (int s = 128; s; s >>= 1) { if (t < s) red[t] += red[t + s]; __syncthreads(); }
    float total = red[0];
    __syncthreads();
    float invx = 1.f / p.nx[b];
    float mx = -1e30f;
    for (int m = t; m < 2048; m += 256) {
        float s = p.simdot[(long long)b * 2048 + m] * invx / p.nm[m];
        mx = fmaxf(mx, s);
    }
    red[t] = mx; __syncthreads();
    for (int s = 128; s; s >>= 1) { if (t < s) red[t] = fmaxf(red[t], red[t + s]); __syncthreads(); }
    if (t == 0) p.sur[b] = (total == 0.f) ? 1.f : 1.f - red[0];
    __syncthreads();
}

// ---------- phase 3a: combine split-m partials + self term ----------
__device__ __forceinline__ void comb_job(const KParams& p, int b) {
    int t = threadIdx.x;
    int h = t >> 5, d = t & 31;
    float qv = frombf(p.qkv_bf[b * 768 + h * 32 + d]);
    float kv = frombf(p.qkv_bf[b * 768 + 256 + h * 32 + d]);
    float sl = qv * kv;
    #pragma unroll
    for (int msk = 1; msk < 32; msk <<= 1) sl += __shfl_xor(sl, msk, 64);
    sl *= SCALE_F;
    float vs = frombf(p.qkv_bf[b * 768 + 512 + h * 32 + d]);
    float ms_[8];
    float Mf = sl;
    #pragma unroll
    for (int s = 0; s < 8; s++) { ms_[s] = p.mpart[(h * 8 + s) * 256 + b]; Mf = fmaxf(Mf, ms_[s]); }
    float es = __expf(sl - Mf);
    float lsum = es, a = es * vs;
    #pragma unroll
    for (int s = 0; s < 8; s++) {
        float wgt = __expf(ms_[s] - Mf);
        lsum += wgt * p.lpart[(h * 8 + s) * 256 + b];
        a += wgt * p.pvpart[((long long)(h * 8 + s) * 256 + b) * 32 + d];
    }
    p.ctx_bf[b * 256 + t] = tobf(a / lsum);
}

// ---------- phase 3b: accept scan (exact closed form + ballot prefix) ----------
// cond(b) = (b < max(0, M - ptr)) || s_b > THR; slot = (ptr + rank) mod M.
__device__ __forceinline__ void accept_job(const KParams& p, short* smem) {
    int t = threadIdx.x;
    for (int m = t; m < 2048; m += 256) p.inv[m] = -1;
    float s = p.sur[t];
    int p0 = p.ptr[0];
    int thresh = 2048 - p0;
    bool cond = (t < thresh) || (s > 0.5f);
    unsigned long long ball = __ballot(cond);
    int lane = t & 63, wv = t >> 6;
    int* ired = (int*)smem;
    if (lane == 0) ired[wv] = __popcll(ball);
    __syncthreads();
    int off = 0;
    for (int i = 0; i < wv; i++) off += ired[i];
    int rank = off + __popcll(ball & ((1ULL << lane) - 1ULL));
    if (cond) p.inv[(p0 + rank) & 2047] = t;
    __syncthreads();
}

// ---------- LayerNorm (k-split reduce + bias + residual) ----------
__device__ __forceinline__ void ln_job(short* smem, const float* parts, int np,
        const float* bias, const float* resid, const float* g, const float* be,
        float* O, short* Ob, int r)
{
    float* red = (float*)smem;
    int t = threadIdx.x;
    float x = bias[t] + resid[r * 256 + t];
    for (int pp = 0; pp < np; pp++) x += parts[(long long)pp * 65536 + r * 256 + t];
    red[t] = x; __syncthreads();
    for (int s = 128; s; s >>= 1) { if (t < s) red[t] += red[t + s]; __syncthreads(); }
    float mean = red[0] * (1.f / 256.f); __syncthreads();
    float c = x - mean;
    red[t] = c * c; __syncthreads();
    for (int s = 128; s; s >>= 1) { if (t < s) red[t] += red[t + s]; __syncthreads(); }
    float rstd = rsqrtf(red[0] * (1.f / 256.f) + 1e-5f);
    float y = c * rstd * g[t] + be[t];
    O[r * 256 + t] = y;
    if (Ob) Ob[r * 256 + t] = tobf(y);
    __syncthreads();
}

// ---------- memory update ----------
__device__ __forceinline__ void memupd_job(const KParams& p, int m) {
    int t = threadIdx.x;
    int b = p.inv[m];
    long long o = (long long)m * 256 + t;
    float xm = p.memory[o], mo = p.momentum[o];
    if (b >= 0) {
        float diff = p.hbuf[b * 256 + t] - xm;
        float nmom = 0.9f * mo + 0.1f * diff;
        p.mem_o[o] = xm + 0.1f * nmom;
        p.mom_o[o] = nmom;
        if (t == 0) p.sc_o[m] = p.sur[b];
    } else {
        p.mem_o[o] = xm;
        p.mom_o[o] = mo;
        if (t == 0) p.sc_o[m] = p.scores[m];
    }
}

// ---------- the single fused cooperative kernel ----------
__global__ __launch_bounds__(256, 2) void fused_k(KParams p) {
    cg::grid_group grid = cg::this_grid();
    __shared__ __align__(16) short smem[29696];   // 59392 B (flash layout is the max)
    int bid = blockIdx.x, gsz = gridDim.x;

    // P0: convert + split packs + row norms
    for (int j = bid; j < 5376; j += gsz) cvt_job(p, smem, j);
    grid.sync();
    // P1: grouped projections (simdot | k | vt | qkv)
    for (int j = bid; j < 432; j += gsz) gemm4_job(p, smem, j);
    grid.sync();
    // P2: flash attention (split-m) || surprise
    for (int j = bid; j < 512; j += gsz) {
        if (j < 256) flash_job(p, smem, j);
        else         surprise_job(p, smem, j - 256);
    }
    grid.sync();
    // P3: combine partials || accept scan
    for (int j = bid; j < 257; j += gsz) {
        if (j < 256) comb_job(p, j);
        else         accept_job(p, smem);
    }
    grid.sync();
    // P4: attn_out partials = ctx @ out_w^T (k-split 8)
    for (int j = bid; j < 128; j += gsz) {
        int ks = j >> 4;
        gemm_tile(smem, p.ctx_bf, 256, p.outw_bf, 256,
                  p.attn_part, nullptr, 256, (long long)ks * 65536, nullptr,
                  256, 256, 32, ks * 32, 1.f, 0, 0, j & 3, (j >> 2) & 3);
    }
    grid.sync();
    // P5: h = LN(src + attn_out + out_b)
    for (int j = bid; j < 256; j += gsz)
        ln_job(smem, p.attn_part, 8, p.out_b, p.src, p.g1, p.be1, p.hbuf, p.hbuf_bf, j);
    grid.sync();
    // P6: ff1 = relu(h @ w1^T + b1) || memory update
    for (int j = bid; j < 2112; j += gsz) {
        if (j < 64) gemm_tile(smem, p.hbuf_bf, 256, p.w1_bf, 256,
                              nullptr, p.ff1_bf, 1024, 0, p.b1,
                              256, 1024, 256, 0, 1.f, 1, 0, j & 15, j >> 4);
        else memupd_job(p, j - 64);
    }
    grid.sync();
    // P7: ff2 partials = ff1 @ w2^T (k-split 16)
    for (int j = bid; j < 256; j += gsz) {
        int ks = j >> 4;
        gemm_tile(smem, p.ff1_bf, 1024, p.w2_bf, 1024,
                  p.ff2_part, nullptr, 256, (long long)ks * 65536, nullptr,
                  256, 256, 64, ks * 64, 1.f, 0, 0, j & 3, (j >> 2) & 3);
    }
    grid.sync();
    // P8: out = LN(h + ff2 + b2)
    for (int j = bid; j < 256; j += gsz)
        ln_job(smem, p.ff2_part, 16, p.b2, p.hbuf, p.g2, p.be2, p.out_main, nullptr, j);
}

extern "C" void kernel_launch(void* const* d_in, const int* in_sizes, int n_in,
                              void* d_out, int out_size, void* d_ws, size_t ws_size,
                              hipStream_t stream)
{
    KParams kp;
    kp.src      = (const float*)d_in[0];
    kp.memory   = (const float*)d_in[1];
    kp.momentum = (const float*)d_in[2];
    kp.scores   = (const float*)d_in[3];
    kp.ipw      = (const float*)d_in[4];
    kp.ipb      = (const float*)d_in[5];
    kp.out_w    = (const float*)d_in[6];
    kp.out_b    = (const float*)d_in[7];
    kp.w1       = (const float*)d_in[8];
    kp.b1       = (const float*)d_in[9];
    kp.w2       = (const float*)d_in[10];
    kp.b2       = (const float*)d_in[11];
    kp.g1       = (const float*)d_in[12];
    kp.be1      = (const float*)d_in[13];
    kp.g2       = (const float*)d_in[14];
    kp.be2      = (const float*)d_in[15];
    kp.ptr      = (const int*)d_in[16];

    float* o = (float*)d_out;
    kp.out_main = o;
    kp.mem_o = o + 65536;
    kp.mom_o = kp.mem_o + 524288;
    kp.sc_o  = kp.mom_o + 524288;

    char* wp = (char*)d_ws;
    auto alloc = [&](size_t n) { void* q = (void*)wp; wp += (n + 255) & ~(size_t)255; return q; };
    kp.srcsplit = (short*)alloc(393216);     // [256][768] (hi|hi|lo)
    kp.memsplit = (short*)alloc(3145728);    // [2048][768] (hi|lo|hi)
    kp.ipw_bf   = (short*)alloc(393216);     // [768][256]
    kp.outw_bf  = (short*)alloc(131072);     // [256][256]
    kp.w1_bf    = (short*)alloc(524288);     // [1024][256]
    kp.w2_bf    = (short*)alloc(524288);     // [256][1024]
    kp.qkv_bf   = (short*)alloc(393216);     // [256][768]
    kp.k_bf     = (short*)alloc(1048576);    // [2048][256]
    kp.vt_bf    = (short*)alloc(1048576);    // [256][2048]
    kp.ctx_bf   = (short*)alloc(131072);     // [256][256]
    kp.hbuf_bf  = (short*)alloc(131072);     // [256][256]
    kp.ff1_bf   = (short*)alloc(524288);     // [256][1024]
    kp.simdot   = (float*)alloc(2097152);    // [256][2048]
    kp.pvpart   = (float*)alloc(2097152);    // [64 S][256 q][32 d]
    kp.mpart    = (float*)alloc(65536);      // [64 S][256 q]
    kp.lpart    = (float*)alloc(65536);
    kp.attn_part= (float*)alloc(2097152);    // [8][256][256]
    kp.ff2_part = (float*)alloc(4194304);    // [16][256][256]
    kp.hbuf     = (float*)alloc(262144);     // [256][256] f32
    kp.nx       = (float*)alloc(1024);
    kp.nm       = (float*)alloc(8192);
    kp.nm2      = (float*)alloc(8192);
    kp.sur      = (float*)alloc(1024);
    kp.inv      = (int*)alloc(8192);

    int nb = 0;
    hipOccupancyMaxActiveBlocksPerMultiprocessor(&nb, fused_k, 256, 0);
    if (nb < 1) nb = 1;
    int grid = nb * 256;
    if (grid > 512) grid = 512;

    void* args[] = { (void*)&kp };
    hipLaunchCooperativeKernel(fused_k, dim3(grid), dim3(256), args, 0, stream);
}

// Round 8
// 154.990 us; speedup vs baseline: 3.9111x; 3.9111x over previous
//
#include <hip/hip_runtime.h>
#include <math.h>

// B=256, D=256, H=8, HD=32, FF=1024, M=2048
#define SCALE_F 0.17677669529663687f

typedef __attribute__((ext_vector_type(8))) short short8;
typedef __attribute__((ext_vector_type(4))) short short4v;
typedef __attribute__((ext_vector_type(4))) float f32x4;

__device__ inline short tobf(float x) {
    unsigned u = __float_as_uint(x);
    unsigned r = (u + 0x7FFFu + ((u >> 16) & 1u)) >> 16;
    return (short)r;
}
__device__ inline float frombf(short s) {
    return __uint_as_float(((unsigned)(unsigned short)s) << 16);
}

// ---------- 1. convert + split packs + row norms (wave-per-row, vectorized) ----------
__global__ __launch_bounds__(256) void cvt2_k(
    const float* __restrict__ src, const float* __restrict__ memory,
    const float* __restrict__ ipw, const float* __restrict__ out_w,
    const float* __restrict__ w1, const float* __restrict__ w2,
    short* __restrict__ srcsplit, short* __restrict__ memsplit,
    short* __restrict__ ipw_bf, short* __restrict__ outw_bf,
    short* __restrict__ w1_bf, short* __restrict__ w2_bf,
    float* __restrict__ nx, float* __restrict__ nm, float* __restrict__ nm2)
{
    int j = blockIdx.x, t = threadIdx.x, w = t >> 6, l = t & 63;
    if (j < 576) {                                  // 2304 rows, 4/block (wave-per-row)
        int r = j * 4 + w;
        bool issrc = r < 256;
        int rr = issrc ? r : r - 256;
        const float* rowp = issrc ? src + (long long)rr * 256 : memory + (long long)rr * 256;
        int c = l * 4;
        float4 x = *(const float4*)(rowp + c);
        short h0 = tobf(x.x), h1 = tobf(x.y), h2 = tobf(x.z), h3 = tobf(x.w);
        short4v hi4 = {h0, h1, h2, h3};
        short4v lo4 = {tobf(x.x - frombf(h0)), tobf(x.y - frombf(h1)),
                       tobf(x.z - frombf(h2)), tobf(x.w - frombf(h3))};
        long long b = (long long)rr * 768;
        if (issrc) {
            *(short4v*)&srcsplit[b + c] = hi4;
            *(short4v*)&srcsplit[b + 256 + c] = hi4;
            *(short4v*)&srcsplit[b + 512 + c] = lo4;
        } else {
            *(short4v*)&memsplit[b + c] = hi4;
            *(short4v*)&memsplit[b + 256 + c] = lo4;
            *(short4v*)&memsplit[b + 512 + c] = hi4;
        }
        float ss = x.x * x.x + x.y * x.y + x.z * x.z + x.w * x.w;
        #pragma unroll
        for (int m = 32; m; m >>= 1) ss += __shfl_xor(ss, m, 64);
        if (l == 0) {
            if (issrc) nx[rr] = fmaxf(sqrtf(ss), 1e-8f);
            else { nm[rr] = fmaxf(sqrtf(ss), 1e-8f); nm2[rr] = ss; }
        }
    } else {                                        // weights: 384 blocks x 2048 elems
        long long base = (long long)(j - 576) * 2048 + t * 8;
        const float* sp; short* dp; long long off;
        if (base < 196608)      { sp = ipw;   dp = ipw_bf;  off = base; }
        else if (base < 262144) { sp = out_w; dp = outw_bf; off = base - 196608; }
        else if (base < 524288) { sp = w1;    dp = w1_bf;   off = base - 262144; }
        else                    { sp = w2;    dp = w2_bf;   off = base - 524288; }
        float4 a = *(const float4*)(sp + off);
        float4 b4 = *(const float4*)(sp + off + 4);
        short8 o = {tobf(a.x), tobf(a.y), tobf(a.z), tobf(a.w),
                    tobf(b4.x), tobf(b4.y), tobf(b4.z), tobf(b4.w)};
        *(short8*)&dp[off] = o;
    }
}

// ---------- shared tile GEMM body: C[M,N] = alpha*A[M,K]@B[N,K]^T ----------
__device__ __forceinline__ void gemm_tile(short* lds,
    const short* __restrict__ A, int lda, const short* __restrict__ B, int ldb,
    float* Cf, short* Cb, int ldc, long long coff, const float* bias,
    int M, int N, int Klen, int kbeg, float alpha, int relu, int transC, int bx, int by)
{
    short* Al = lds;           // [64][40]
    short* Bl = lds + 2560;    // [64][40]
    int t = threadIdx.x, w = t >> 6, l = t & 63;
    int r0 = by * 64, c0 = bx * 64;
    int srow = t >> 2, scol = (t & 3) * 8;
    f32x4 acc[4] = {{0.f,0.f,0.f,0.f},{0.f,0.f,0.f,0.f},{0.f,0.f,0.f,0.f},{0.f,0.f,0.f,0.f}};
    for (int kk = 0; kk < Klen; kk += 32) {
        int k0 = kbeg + kk;
        short8 va = {0,0,0,0,0,0,0,0};
        if (r0 + srow < M) va = *(const short8*)(A + (long long)(r0 + srow) * lda + k0 + scol);
        *(short8*)&Al[srow * 40 + scol] = va;
        short8 vb = {0,0,0,0,0,0,0,0};
        if (c0 + srow < N) vb = *(const short8*)(B + (long long)(c0 + srow) * ldb + k0 + scol);
        *(short8*)&Bl[srow * 40 + scol] = vb;
        __syncthreads();
        short8 af = *(const short8*)&Al[(w * 16 + (l & 15)) * 40 + (l >> 4) * 8];
        #pragma unroll
        for (int j = 0; j < 4; j++) {
            short8 bf = *(const short8*)&Bl[(j * 16 + (l & 15)) * 40 + (l >> 4) * 8];
            acc[j] = __builtin_amdgcn_mfma_f32_16x16x32_bf16(af, bf, acc[j], 0, 0, 0);
        }
        __syncthreads();
    }
    int lc = l & 15, lr = (l >> 4) * 4;
    #pragma unroll
    for (int j = 0; j < 4; j++) {
        int col = c0 + j * 16 + lc;
        if (col >= N) continue;
        float bv = bias ? bias[col] : 0.f;
        #pragma unroll
        for (int r = 0; r < 4; r++) {
            int row = r0 + w * 16 + lr + r;
            if (row >= M) continue;
            float v = acc[j][r] * alpha + bv;
            if (relu) v = fmaxf(v, 0.f);
            long long idx = coff + (transC ? (long long)col * ldc + row
                                           : (long long)row * ldc + col);
            if (Cf) Cf[idx] = v;
            else    Cb[idx] = tobf(v);
        }
    }
}

// ---------- 2. grouped projections: simdot | k_bf | vt_bf | qkv ----------
__global__ __launch_bounds__(256) void gemm4_k(
    const short* __restrict__ srcsplit, const short* __restrict__ memsplit,
    const short* __restrict__ ipw_bf, const float* __restrict__ ipb,
    float* __restrict__ simdot, short* __restrict__ qkv_bf,
    short* __restrict__ k_bf, short* __restrict__ vt_bf)
{
    __shared__ short lds[5120];
    int bid = blockIdx.x;
    const short *A, *B; const float *bias; float *Cf; short *Cb;
    int lda, ldb, ldc, M, N, K, transC, bx, by;
    if (bid < 128) {            // simdot = srcsplit @ memsplit^T (K=768 split trick)
        A = srcsplit; lda = 768; B = memsplit; ldb = 768;
        Cf = simdot; Cb = nullptr; ldc = 2048; bias = nullptr;
        M = 256; N = 2048; K = 768; transC = 0;
        bx = bid & 31; by = bid >> 5;
    } else if (bid < 256) {     // k_bf = mem_hi @ Wk^T + bk
        int r = bid - 128;
        A = memsplit + 512; lda = 768; B = ipw_bf + 65536; ldb = 256;
        Cf = nullptr; Cb = k_bf; ldc = 256; bias = ipb + 256;
        M = 2048; N = 256; K = 256; transC = 0;
        bx = r & 3; by = r >> 2;
    } else if (bid < 384) {     // vt_bf = (mem_hi @ Wv^T + bv)^T
        int r = bid - 256;
        A = memsplit + 512; lda = 768; B = ipw_bf + 131072; ldb = 256;
        Cf = nullptr; Cb = vt_bf; ldc = 2048; bias = ipb + 512;
        M = 2048; N = 256; K = 256; transC = 1;
        bx = r & 3; by = r >> 2;
    } else {                    // qkv_bf = src_hi @ ipw^T + ipb
        int r = bid - 384;
        A = srcsplit; lda = 768; B = ipw_bf; ldb = 256;
        Cf = nullptr; Cb = qkv_bf; ldc = 768; bias = ipb;
        M = 256; N = 768; K = 256; transC = 0;
        bx = r % 12; by = r / 12;
    }
    gemm_tile(lds, A, lda, B, ldb, Cf, Cb, ldc, 0, bias, M, N, K, 0, 1.f, 0, transC, bx, by);
}

// ---------- 3. flash attention (split-m) || surprise ----------
__global__ __launch_bounds__(256) void flash_sur_k(
    const short* __restrict__ qkv_bf, const short* __restrict__ k_bf,
    const short* __restrict__ vt_bf,
    float* __restrict__ pvpart, float* __restrict__ mpart, float* __restrict__ lpart,
    const float* __restrict__ simdot, const float* __restrict__ nx,
    const float* __restrict__ nm, const float* __restrict__ nm2, float* __restrict__ sur)
{
    __shared__ __align__(16) short smem[29696];
    int bid = blockIdx.x;
    int t = threadIdx.x;
    if (bid >= 256) {           // surprise
        float* red = (float*)smem;
        int b = bid - 256;
        float tot = 0.f;
        for (int m = t; m < 2048; m += 256) tot += nm2[m];
        red[t] = tot; __syncthreads();
        for (int s = 128; s; s >>= 1) { if (t < s) red[t] += red[t + s]; __syncthreads(); }
        float total = red[0];
        __syncthreads();
        float invx = 1.f / nx[b];
        float mx = -1e30f;
        for (int m = t; m < 2048; m += 256) {
            float s = simdot[(long long)b * 2048 + m] * invx / nm[m];
            mx = fmaxf(mx, s);
        }
        red[t] = mx; __syncthreads();
        for (int s = 128; s; s >>= 1) { if (t < s) red[t] = fmaxf(red[t], red[t + s]); __syncthreads(); }
        if (t == 0) sur[b] = (total == 0.f) ? 1.f : 1.f - red[0];
        return;
    }
    int ms = bid & 7, h = (bid >> 3) & 7, qt = bid >> 6;
    int q0 = qt * 64, m0 = ms * 256;
    int S = bid & 63;
    int w = t >> 6, l = t & 63;
    short* Ql = smem;            // [64][40]
    short* Kl = smem + 2560;     // [256][40]
    short* Pl = smem + 12800;    // [64][264]
    { int srow = t >> 2, scol = (t & 3) * 8;
      *(short8*)&Ql[srow * 40 + scol] = *(const short8*)(qkv_bf + (q0 + srow) * 768 + h * 32 + scol); }
    #pragma unroll
    for (int s = 0; s < 4; s++) {
        int seg = t + s * 256; int row = seg >> 2, off = (seg & 3) * 8;
        *(short8*)&Kl[row * 40 + off] = *(const short8*)(k_bf + (long long)(m0 + row) * 256 + h * 32 + off);
    }
    __syncthreads();
    short8 af = *(const short8*)&Ql[(w * 16 + (l & 15)) * 40 + (l >> 4) * 8];
    f32x4 accL[16];
    #pragma unroll
    for (int j = 0; j < 16; j++) accL[j] = f32x4{0.f, 0.f, 0.f, 0.f};
    #pragma unroll
    for (int j = 0; j < 16; j++) {
        short8 bf = *(const short8*)&Kl[(j * 16 + (l & 15)) * 40 + (l >> 4) * 8];
        accL[j] = __builtin_amdgcn_mfma_f32_16x16x32_bf16(af, bf, accL[j], 0, 0, 0);
    }
    int r4 = (l >> 4) * 4;
    float mloc[4], lsum[4];
    #pragma unroll
    for (int r = 0; r < 4; r++) {
        float mx = -1e30f;
        #pragma unroll
        for (int j = 0; j < 16; j++) mx = fmaxf(mx, accL[j][r] * SCALE_F);
        #pragma unroll
        for (int msk = 1; msk < 16; msk <<= 1) mx = fmaxf(mx, __shfl_xor(mx, msk, 64));
        mloc[r] = mx;
    }
    #pragma unroll
    for (int j = 0; j < 16; j++)
        #pragma unroll
        for (int r = 0; r < 4; r++)
            accL[j][r] = __expf(accL[j][r] * SCALE_F - mloc[r]);
    #pragma unroll
    for (int r = 0; r < 4; r++) {
        float ls = 0.f;
        #pragma unroll
        for (int j = 0; j < 16; j++) ls += accL[j][r];
        #pragma unroll
        for (int msk = 1; msk < 16; msk <<= 1) ls += __shfl_xor(ls, msk, 64);
        lsum[r] = ls;
    }
    if ((l & 15) == 0) {
        #pragma unroll
        for (int r = 0; r < 4; r++) {
            int gq = q0 + w * 16 + r4 + r;
            mpart[S * 256 + gq] = mloc[r];
            lpart[S * 256 + gq] = lsum[r];
        }
    }
    #pragma unroll
    for (int j = 0; j < 16; j++)
        #pragma unroll
        for (int r = 0; r < 4; r++)
            Pl[(w * 16 + r4 + r) * 264 + j * 16 + (l & 15)] = tobf(accL[j][r]);
    __syncthreads();
    f32x4 accP[2] = {{0.f,0.f,0.f,0.f},{0.f,0.f,0.f,0.f}};
    #pragma unroll
    for (int ks = 0; ks < 8; ks++) {
        short8 pa = *(const short8*)&Pl[(w * 16 + (l & 15)) * 264 + ks * 32 + (l >> 4) * 8];
        #pragma unroll
        for (int df = 0; df < 2; df++) {
            short8 vb = *(const short8*)(vt_bf + (long long)(h * 32 + df * 16 + (l & 15)) * 2048
                                         + m0 + ks * 32 + (l >> 4) * 8);
            accP[df] = __builtin_amdgcn_mfma_f32_16x16x32_bf16(pa, vb, accP[df], 0, 0, 0);
        }
    }
    #pragma unroll
    for (int df = 0; df < 2; df++)
        #pragma unroll
        for (int r = 0; r < 4; r++) {
            int gq = q0 + w * 16 + r4 + r;
            pvpart[((long long)S * 256 + gq) * 32 + df * 16 + (l & 15)] = accP[df][r];
        }
}

// ---------- 4. attn-out GEMM with inline combine (+ accept scan block) ----------
// j<128: (h=j>>4, bx=j&3, by=(j>>2)&3): A-tile = ctx[64 rows][head h's 32 cols]
// built in-block from pvpart + softmax stats; one 32-k MFMA step vs out_w.
__global__ __launch_bounds__(256) void attn_gemm_k(
    const short* __restrict__ qkv_bf, const float* __restrict__ mpart,
    const float* __restrict__ lpart, const float* __restrict__ pvpart,
    const short* __restrict__ outw_bf, float* __restrict__ attn_part,
    const float* __restrict__ sur, const int* __restrict__ ptr, int* __restrict__ inv)
{
    __shared__ float ws_n[64][8];
    __shared__ float es_n[64];
    __shared__ short Al[2560];
    __shared__ short Bl[2560];
    int j = blockIdx.x, t = threadIdx.x;
    if (j >= 128) {             // accept scan (closed form + ballot prefix)
        int* ired = (int*)ws_n;
        for (int m = t; m < 2048; m += 256) inv[m] = -1;
        float s = sur[t];
        int p0 = ptr[0];
        int thresh = 2048 - p0;
        bool cond = (t < thresh) || (s > 0.5f);
        unsigned long long ball = __ballot(cond);
        int lane = t & 63, wv = t >> 6;
        if (lane == 0) ired[wv] = __popcll(ball);
        __syncthreads();
        int off = 0;
        for (int i = 0; i < wv; i++) off += ired[i];
        int rank = off + __popcll(ball & ((1ULL << lane) - 1ULL));
        if (cond) inv[(p0 + rank) & 2047] = t;
        return;
    }
    int h = j >> 4, r = j & 15, bx = r & 3, by = r >> 2;
    int b0 = by * 64, c0 = bx * 64;
    // stats: per row, self logit + combine weights (8 passes of 8 rows)
    #pragma unroll
    for (int p = 0; p < 8; p++) {
        int rl = p * 8 + (t >> 5);
        int lane32 = t & 31;
        int b = b0 + rl;
        float q = frombf(qkv_bf[b * 768 + h * 32 + lane32]);
        float k = frombf(qkv_bf[b * 768 + 256 + h * 32 + lane32]);
        float prod = q * k;
        #pragma unroll
        for (int m = 16; m; m >>= 1) prod += __shfl_xor(prod, m, 64);
        float sl = prod * SCALE_F;
        if (lane32 < 8) {
            int S = h * 8 + lane32;
            float msv = mpart[S * 256 + b];
            float lpv = lpart[S * 256 + b];
            float mx = msv;
            #pragma unroll
            for (int m = 4; m; m >>= 1) mx = fmaxf(mx, __shfl_xor(mx, m, 64));
            float Mf = fmaxf(mx, sl);
            float wgt = __expf(msv - Mf);
            float suml = wgt * lpv;
            #pragma unroll
            for (int m = 4; m; m >>= 1) suml += __shfl_xor(suml, m, 64);
            float Es = __expf(sl - Mf);
            float Ls = suml + Es;
            ws_n[rl][lane32] = wgt / Ls;
            if (lane32 == 0) es_n[rl] = Es / Ls;
        }
    }
    __syncthreads();
    // build A-tile (ctx) + stage B
    {
        int rl = t >> 2, cg = (t & 3) * 8;
        int b = b0 + rl;
        short8 vs8 = *(const short8*)(qkv_bf + b * 768 + 512 + h * 32 + cg);
        float es = es_n[rl];
        float a8[8];
        #pragma unroll
        for (int d = 0; d < 8; d++) a8[d] = es * frombf(vs8[d]);
        #pragma unroll
        for (int s = 0; s < 8; s++) {
            float wn = ws_n[rl][s];
            const float* pvb = pvpart + ((long long)(h * 8 + s) * 256 + b) * 32 + cg;
            float4 p0 = *(const float4*)pvb;
            float4 p1 = *(const float4*)(pvb + 4);
            a8[0] += wn * p0.x; a8[1] += wn * p0.y; a8[2] += wn * p0.z; a8[3] += wn * p0.w;
            a8[4] += wn * p1.x; a8[5] += wn * p1.y; a8[6] += wn * p1.z; a8[7] += wn * p1.w;
        }
        short8 o = {tobf(a8[0]), tobf(a8[1]), tobf(a8[2]), tobf(a8[3]),
                    tobf(a8[4]), tobf(a8[5]), tobf(a8[6]), tobf(a8[7])};
        *(short8*)&Al[rl * 40 + cg] = o;
        *(short8*)&Bl[rl * 40 + cg] = *(const short8*)(outw_bf + (long long)(c0 + rl) * 256 + h * 32 + cg);
    }
    __syncthreads();
    int w = t >> 6, l = t & 63;
    short8 af = *(const short8*)&Al[(w * 16 + (l & 15)) * 40 + (l >> 4) * 8];
    f32x4 acc[4] = {{0.f,0.f,0.f,0.f},{0.f,0.f,0.f,0.f},{0.f,0.f,0.f,0.f},{0.f,0.f,0.f,0.f}};
    #pragma unroll
    for (int j4 = 0; j4 < 4; j4++) {
        short8 bf = *(const short8*)&Bl[(j4 * 16 + (l & 15)) * 40 + (l >> 4) * 8];
        acc[j4] = __builtin_amdgcn_mfma_f32_16x16x32_bf16(af, bf, acc[j4], 0, 0, 0);
    }
    int lc = l & 15, lr = (l >> 4) * 4;
    #pragma unroll
    for (int j4 = 0; j4 < 4; j4++) {
        int col = c0 + j4 * 16 + lc;
        #pragma unroll
        for (int rr = 0; rr < 4; rr++) {
            int row = b0 + w * 16 + lr + rr;
            attn_part[(long long)h * 65536 + row * 256 + col] = acc[j4][rr];
        }
    }
}

// ---------- 5. ff1 GEMM with inline LayerNorm A-staging ----------
__global__ __launch_bounds__(256) void ff1_ln_k(
    const float* __restrict__ attn_part, const float* __restrict__ out_b,
    const float* __restrict__ src, const float* __restrict__ g1,
    const float* __restrict__ be1, const short* __restrict__ w1_bf,
    const float* __restrict__ b1, float* __restrict__ hbuf, short* __restrict__ ff1_bf)
{
    __shared__ short Afull[64 * 264];
    __shared__ short Bl[2560];
    int bx = blockIdx.x, by = blockIdx.y;
    int t = threadIdx.x, w = t >> 6, l = t & 63;
    // LN rows by*64..+64 (wave-per-row, shfl reduce, no syncthreads)
    #pragma unroll
    for (int p = 0; p < 16; p++) {
        int rl = p * 4 + w;
        int r = by * 64 + rl;
        int c = l * 4;
        float4 x = *(const float4*)(out_b + c);
        float4 sv = *(const float4*)(src + (long long)r * 256 + c);
        x.x += sv.x; x.y += sv.y; x.z += sv.z; x.w += sv.w;
        #pragma unroll
        for (int pp = 0; pp < 8; pp++) {
            float4 a = *(const float4*)(attn_part + (long long)pp * 65536 + r * 256 + c);
            x.x += a.x; x.y += a.y; x.z += a.z; x.w += a.w;
        }
        float s = x.x + x.y + x.z + x.w;
        #pragma unroll
        for (int m = 32; m; m >>= 1) s += __shfl_xor(s, m, 64);
        float mean = s * (1.f / 256.f);
        float4 cv = {x.x - mean, x.y - mean, x.z - mean, x.w - mean};
        float ss = cv.x * cv.x + cv.y * cv.y + cv.z * cv.z + cv.w * cv.w;
        #pragma unroll
        for (int m = 32; m; m >>= 1) ss += __shfl_xor(ss, m, 64);
        float rstd = rsqrtf(ss * (1.f / 256.f) + 1e-5f);
        float4 gg = *(const float4*)(g1 + c);
        float4 bb = *(const float4*)(be1 + c);
        float4 y = {cv.x * rstd * gg.x + bb.x, cv.y * rstd * gg.y + bb.y,
                    cv.z * rstd * gg.z + bb.z, cv.w * rstd * gg.w + bb.w};
        if (bx == 0) *(float4*)(hbuf + (long long)r * 256 + c) = y;
        short4v yb = {tobf(y.x), tobf(y.y), tobf(y.z), tobf(y.w)};
        *(short4v*)&Afull[rl * 264 + c] = yb;
    }
    __syncthreads();
    int c0 = bx * 64;
    int srow = t >> 2, scol = (t & 3) * 8;
    f32x4 acc[4] = {{0.f,0.f,0.f,0.f},{0.f,0.f,0.f,0.f},{0.f,0.f,0.f,0.f},{0.f,0.f,0.f,0.f}};
    for (int kk = 0; kk < 256; kk += 32) {
        *(short8*)&Bl[srow * 40 + scol] = *(const short8*)(w1_bf + (long long)(c0 + srow) * 256 + kk + scol);
        __syncthreads();
        short8 af = *(const short8*)&Afull[(w * 16 + (l & 15)) * 264 + kk + (l >> 4) * 8];
        #pragma unroll
        for (int j = 0; j < 4; j++) {
            short8 bf = *(const short8*)&Bl[(j * 16 + (l & 15)) * 40 + (l >> 4) * 8];
            acc[j] = __builtin_amdgcn_mfma_f32_16x16x32_bf16(af, bf, acc[j], 0, 0, 0);
        }
        __syncthreads();
    }
    int lc = l & 15, lr = (l >> 4) * 4;
    #pragma unroll
    for (int j = 0; j < 4; j++) {
        int col = c0 + j * 16 + lc;
        float bv = b1[col];
        #pragma unroll
        for (int r = 0; r < 4; r++) {
            int row = by * 64 + w * 16 + lr + r;
            float v = fmaxf(acc[j][r] + bv, 0.f);
            ff1_bf[(long long)row * 1024 + col] = tobf(v);
        }
    }
}

// ---------- 6. ff2 GEMM (k-split 8) || memory update (vectorized) ----------
__global__ __launch_bounds__(256) void ff2_mem_k(
    const short* __restrict__ ff1_bf, const short* __restrict__ w2_bf,
    float* __restrict__ ff2_part,
    const float* __restrict__ memory, const float* __restrict__ momentum,
    const float* __restrict__ scores, const float* __restrict__ hbuf,
    const float* __restrict__ sur, const int* __restrict__ inv,
    float* __restrict__ mem_o, float* __restrict__ mom_o, float* __restrict__ sc_o)
{
    __shared__ short lds[5120];
    int j = blockIdx.x, t = threadIdx.x;
    if (j < 128) {
        int ks = j >> 4, r = j & 15, bx = r & 3, by = r >> 2;
        gemm_tile(lds, ff1_bf, 1024, w2_bf, 1024, ff2_part, nullptr, 256,
                  (long long)ks * 65536, nullptr, 256, 256, 128, ks * 128, 1.f, 0, 0, bx, by);
        return;
    }
    int w = t >> 6, l = t & 63;
    int m = (j - 128) * 4 + w;
    int b = inv[m];
    long long o = (long long)m * 256 + l * 4;
    float4 xm = *(const float4*)(memory + o);
    float4 mo = *(const float4*)(momentum + o);
    if (b >= 0) {
        float4 hb = *(const float4*)(hbuf + (long long)b * 256 + l * 4);
        float4 nmom = {0.9f * mo.x + 0.1f * (hb.x - xm.x), 0.9f * mo.y + 0.1f * (hb.y - xm.y),
                       0.9f * mo.z + 0.1f * (hb.z - xm.z), 0.9f * mo.w + 0.1f * (hb.w - xm.w)};
        float4 nm4 = {xm.x + 0.1f * nmom.x, xm.y + 0.1f * nmom.y,
                      xm.z + 0.1f * nmom.z, xm.w + 0.1f * nmom.w};
        *(float4*)(mem_o + o) = nm4;
        *(float4*)(mom_o + o) = nmom;
        if (l == 0) sc_o[m] = sur[b];
    } else {
        *(float4*)(mem_o + o) = xm;
        *(float4*)(mom_o + o) = mo;
        if (l == 0) sc_o[m] = scores[m];
    }
}

// ---------- 7. final LayerNorm (wave-per-row) ----------
__global__ __launch_bounds__(256) void ln2_k(
    const float* __restrict__ ff2_part, const float* __restrict__ b2,
    const float* __restrict__ hbuf, const float* __restrict__ g2,
    const float* __restrict__ be2, float* __restrict__ out_main)
{
    int t = threadIdx.x, w = t >> 6, l = t & 63;
    int r = blockIdx.x * 4 + w;
    int c = l * 4;
    float4 x = *(const float4*)(b2 + c);
    float4 hv = *(const float4*)(hbuf + (long long)r * 256 + c);
    x.x += hv.x; x.y += hv.y; x.z += hv.z; x.w += hv.w;
    #pragma unroll
    for (int pp = 0; pp < 8; pp++) {
        float4 a = *(const float4*)(ff2_part + (long long)pp * 65536 + r * 256 + c);
        x.x += a.x; x.y += a.y; x.z += a.z; x.w += a.w;
    }
    float s = x.x + x.y + x.z + x.w;
    #pragma unroll
    for (int m = 32; m; m >>= 1) s += __shfl_xor(s, m, 64);
    float mean = s * (1.f / 256.f);
    float4 cv = {x.x - mean, x.y - mean, x.z - mean, x.w - mean};
    float ss = cv.x * cv.x + cv.y * cv.y + cv.z * cv.z + cv.w * cv.w;
    #pragma unroll
    for (int m = 32; m; m >>= 1) ss += __shfl_xor(ss, m, 64);
    float rstd = rsqrtf(ss * (1.f / 256.f) + 1e-5f);
    float4 gg = *(const float4*)(g2 + c);
    float4 bb = *(const float4*)(be2 + c);
    float4 y = {cv.x * rstd * gg.x + bb.x, cv.y * rstd * gg.y + bb.y,
                cv.z * rstd * gg.z + bb.z, cv.w * rstd * gg.w + bb.w};
    *(float4*)(out_main + (long long)r * 256 + c) = y;
}

extern "C" void kernel_launch(void* const* d_in, const int* in_sizes, int n_in,
                              void* d_out, int out_size, void* d_ws, size_t ws_size,
                              hipStream_t stream)
{
    const float* src      = (const float*)d_in[0];
    const float* memory   = (const float*)d_in[1];
    const float* momentum = (const float*)d_in[2];
    const float* scores   = (const float*)d_in[3];
    const float* ipw      = (const float*)d_in[4];
    const float* ipb      = (const float*)d_in[5];
    const float* out_w    = (const float*)d_in[6];
    const float* out_b    = (const float*)d_in[7];
    const float* w1       = (const float*)d_in[8];
    const float* b1       = (const float*)d_in[9];
    const float* w2       = (const float*)d_in[10];
    const float* b2       = (const float*)d_in[11];
    const float* g1       = (const float*)d_in[12];
    const float* be1      = (const float*)d_in[13];
    const float* g2       = (const float*)d_in[14];
    const float* be2      = (const float*)d_in[15];
    const int*   ptr      = (const int*)d_in[16];

    float* o = (float*)d_out;
    float* out_main = o;
    float* mem_o = o + 65536;
    float* mom_o = mem_o + 524288;
    float* sc_o  = mom_o + 524288;

    char* wp = (char*)d_ws;
    auto alloc = [&](size_t n) { void* q = (void*)wp; wp += (n + 255) & ~(size_t)255; return q; };
    short* srcsplit = (short*)alloc(393216);     // [256][768] (hi|hi|lo)
    short* memsplit = (short*)alloc(3145728);    // [2048][768] (hi|lo|hi)
    short* ipw_bf   = (short*)alloc(393216);     // [768][256]
    short* outw_bf  = (short*)alloc(131072);     // [256][256]
    short* w1_bf    = (short*)alloc(524288);     // [1024][256]
    short* w2_bf    = (short*)alloc(524288);     // [256][1024]
    short* qkv_bf   = (short*)alloc(393216);     // [256][768]
    short* k_bf     = (short*)alloc(1048576);    // [2048][256]
    short* vt_bf    = (short*)alloc(1048576);    // [256][2048]
    short* ff1_bf   = (short*)alloc(524288);     // [256][1024]
    float* simdot   = (float*)alloc(2097152);    // [256][2048]
    float* pvpart   = (float*)alloc(2097152);    // [64 S][256 q][32 d]
    float* mpart    = (float*)alloc(65536);      // [64 S][256 q]
    float* lpart    = (float*)alloc(65536);
    float* attn_part= (float*)alloc(2097152);    // [8][256][256]
    float* ff2_part = (float*)alloc(2097152);    // [8][256][256]
    float* hbuf     = (float*)alloc(262144);     // [256][256] f32
    float* nx       = (float*)alloc(1024);
    float* nm       = (float*)alloc(8192);
    float* nm2      = (float*)alloc(8192);
    float* sur      = (float*)alloc(1024);
    int*   inv      = (int*)alloc(8192);

    // 1. convert + split packs + row norms
    cvt2_k<<<960, 256, 0, stream>>>(src, memory, ipw, out_w, w1, w2,
        srcsplit, memsplit, ipw_bf, outw_bf, w1_bf, w2_bf, nx, nm, nm2);
    // 2. grouped projections
    gemm4_k<<<432, 256, 0, stream>>>(srcsplit, memsplit, ipw_bf, ipb,
        simdot, qkv_bf, k_bf, vt_bf);
    // 3. flash attention || surprise
    flash_sur_k<<<512, 256, 0, stream>>>(qkv_bf, k_bf, vt_bf, pvpart, mpart, lpart,
        simdot, nx, nm, nm2, sur);
    // 4. attn-out GEMM (inline combine) + accept scan
    attn_gemm_k<<<129, 256, 0, stream>>>(qkv_bf, mpart, lpart, pvpart, outw_bf,
        attn_part, sur, ptr, inv);
    // 5. ff1 GEMM (inline LN1; bx==0 writes hbuf)
    ff1_ln_k<<<dim3(16, 4), 256, 0, stream>>>(attn_part, out_b, src, g1, be1,
        w1_bf, b1, hbuf, ff1_bf);
    // 6. ff2 GEMM || memory update
    ff2_mem_k<<<640, 256, 0, stream>>>(ff1_bf, w2_bf, ff2_part,
        memory, momentum, scores, hbuf, sur, inv, mem_o, mom_o, sc_o);
    // 7. final LN
    ln2_k<<<64, 256, 0, stream>>>(ff2_part, b2, hbuf, g2, be2, out_main);
}

// Round 9
// 145.932 us; speedup vs baseline: 4.1538x; 1.0621x over previous
//
#include <hip/hip_runtime.h>
#include <math.h>

// B=256, D=256, H=8, FF=1024, M=2048
#define SCALE_F 0.17677669529663687f

typedef __attribute__((ext_vector_type(8))) short short8;
typedef __attribute__((ext_vector_type(4))) short short4v;
typedef __attribute__((ext_vector_type(4))) float f32x4;

__device__ inline short tobf(float x) {
    unsigned u = __float_as_uint(x);
    unsigned r = (u + 0x7FFFu + ((u >> 16) & 1u)) >> 16;
    return (short)r;
}
__device__ inline float frombf(short s) {
    return __uint_as_float(((unsigned)(unsigned short)s) << 16);
}

// convert 8 f32 -> bf16 (hi) or residual-lo
__device__ __forceinline__ short8 cv8(const float* __restrict__ p, int lo) {
    float4 a = *(const float4*)p, b = *(const float4*)(p + 4);
    float xs[8] = {a.x, a.y, a.z, a.w, b.x, b.y, b.z, b.w};
    short8 o;
    #pragma unroll
    for (int i = 0; i < 8; i++) {
        short hi = tobf(xs[i]);
        o[i] = lo ? tobf(xs[i] - frombf(hi)) : hi;
    }
    return o;
}

// ---------- staged-convert GEMM body: C = A_f32(cv) @ B_f32(cv)^T, K=256 ----------
__device__ __forceinline__ void gemm_cv(short* lds,
    const float* __restrict__ A, int lda, int aLo,
    const float* __restrict__ B, int ldb, int bLo,
    float* Cf, short* Cb, int ldc, const float* bias, int transC, int bx, int by)
{
    short* Al = lds;           // [64][40]
    short* Bl = lds + 2560;    // [64][40]
    int t = threadIdx.x, w = t >> 6, l = t & 63;
    int r0 = by * 64, c0 = bx * 64;
    int srow = t >> 2, scol = (t & 3) * 8;
    f32x4 acc[4] = {{0.f,0.f,0.f,0.f},{0.f,0.f,0.f,0.f},{0.f,0.f,0.f,0.f},{0.f,0.f,0.f,0.f}};
    for (int kk = 0; kk < 256; kk += 32) {
        *(short8*)&Al[srow * 40 + scol] = cv8(A + (long long)(r0 + srow) * lda + kk + scol, aLo);
        *(short8*)&Bl[srow * 40 + scol] = cv8(B + (long long)(c0 + srow) * ldb + kk + scol, bLo);
        __syncthreads();
        short8 af = *(const short8*)&Al[(w * 16 + (l & 15)) * 40 + (l >> 4) * 8];
        #pragma unroll
        for (int j = 0; j < 4; j++) {
            short8 bf = *(const short8*)&Bl[(j * 16 + (l & 15)) * 40 + (l >> 4) * 8];
            acc[j] = __builtin_amdgcn_mfma_f32_16x16x32_bf16(af, bf, acc[j], 0, 0, 0);
        }
        __syncthreads();
    }
    int lc = l & 15, lr = (l >> 4) * 4;
    #pragma unroll
    for (int j = 0; j < 4; j++) {
        int col = c0 + j * 16 + lc;
        float bv = bias ? bias[col] : 0.f;
        #pragma unroll
        for (int r = 0; r < 4; r++) {
            int row = r0 + w * 16 + lr + r;
            float v = acc[j][r] + bv;
            long long idx = transC ? (long long)col * ldc + row : (long long)row * ldc + col;
            if (Cf) Cf[idx] = v;
            else    Cb[idx] = tobf(v);
        }
    }
}

// ---------- 1. projections + conversions + norms, one launch (868 blocks) ----------
// 0..383   simdot term t=bid/128 (hi*hi | hi*lo | lo*hi) -> simdot_p[t]
// 384..511 k_bf = mem_hi @ Wk^T + bk
// 512..639 vt_bf = (mem_hi @ Wv^T + bv)^T
// 640..687 qkv_bf = src_hi @ ipw^T + ipb
// 688..723 row norms (64 rows/block)
// 724..867 weight cvt (outw|w1|w2, 4096 elems/block)
__global__ __launch_bounds__(256) void proj_k(
    const float* __restrict__ src, const float* __restrict__ memory,
    const float* __restrict__ ipw, const float* __restrict__ ipb,
    const float* __restrict__ out_w, const float* __restrict__ w1, const float* __restrict__ w2,
    float* __restrict__ simdot_p, short* __restrict__ qkv_bf,
    short* __restrict__ k_bf, short* __restrict__ vt_bf,
    short* __restrict__ outw_bf, short* __restrict__ w1_bf, short* __restrict__ w2_bf,
    float* __restrict__ nx, float* __restrict__ nm, float* __restrict__ nm2)
{
    __shared__ short lds[5120];
    int bid = blockIdx.x, t = threadIdx.x, w = t >> 6, l = t & 63;
    if (bid < 384) {
        int tm = bid >> 7, r = bid & 127;
        int aLo = (tm == 2), bLo = (tm == 1);
        gemm_cv(lds, src, 256, aLo, memory, 256, bLo,
                simdot_p + (long long)tm * 524288, nullptr, 2048, nullptr, 0, r & 31, r >> 5);
    } else if (bid < 512) {
        int r = bid - 384;
        gemm_cv(lds, memory, 256, 0, ipw + 65536, 256, 0,
                nullptr, k_bf, 256, ipb + 256, 0, r & 3, r >> 2);
    } else if (bid < 640) {
        int r = bid - 512;
        gemm_cv(lds, memory, 256, 0, ipw + 131072, 256, 0,
                nullptr, vt_bf, 2048, ipb + 512, 1, r & 3, r >> 2);
    } else if (bid < 688) {
        int r = bid - 640;
        gemm_cv(lds, src, 256, 0, ipw, 256, 0,
                nullptr, qkv_bf, 768, ipb, 0, r % 12, r / 12);
    } else if (bid < 724) {
        int nb = bid - 688;
        #pragma unroll
        for (int i = 0; i < 16; i++) {
            int r = nb * 64 + i * 4 + w;
            bool issrc = r < 256;
            int rr = issrc ? r : r - 256;
            const float* rowp = issrc ? src + (long long)rr * 256 : memory + (long long)rr * 256;
            float4 x = *(const float4*)(rowp + l * 4);
            float ss = x.x * x.x + x.y * x.y + x.z * x.z + x.w * x.w;
            #pragma unroll
            for (int m = 32; m; m >>= 1) ss += __shfl_xor(ss, m, 64);
            if (l == 0) {
                if (issrc) nx[rr] = fmaxf(sqrtf(ss), 1e-8f);
                else { nm[rr] = fmaxf(sqrtf(ss), 1e-8f); nm2[rr] = ss; }
            }
        }
    } else {
        long long base = (long long)(bid - 724) * 4096 + t * 8;
        #pragma unroll
        for (int rep = 0; rep < 2; rep++) {
            long long e = base + rep * 2048;
            const float* sp; short* dp; long long off;
            if (e < 65536)       { sp = out_w; dp = outw_bf; off = e; }
            else if (e < 327680) { sp = w1;    dp = w1_bf;   off = e - 65536; }
            else                 { sp = w2;    dp = w2_bf;   off = e - 327680; }
            *(short8*)&dp[off] = cv8(sp + off, 0);
        }
    }
}

// ---------- 2. flash attention (split-m, 44KB LDS -> 3 blocks/CU) || surprise ----------
__global__ __launch_bounds__(256) void flash_sur_k(
    const short* __restrict__ qkv_bf, const short* __restrict__ k_bf,
    const short* __restrict__ vt_bf,
    float* __restrict__ pvpart, float* __restrict__ mpart, float* __restrict__ lpart,
    const float* __restrict__ simdot_p, const float* __restrict__ nx,
    const float* __restrict__ nm, const float* __restrict__ nm2, float* __restrict__ sur)
{
    __shared__ __align__(16) short smem[22016];   // Kl [128][40] | Pl [64][264]
    int bid = blockIdx.x, t = threadIdx.x;
    if (bid >= 256) {           // surprise
        float* red = (float*)smem;
        int b = bid - 256;
        float tot = 0.f;
        for (int m = t; m < 2048; m += 256) tot += nm2[m];
        red[t] = tot; __syncthreads();
        for (int s = 128; s; s >>= 1) { if (t < s) red[t] += red[t + s]; __syncthreads(); }
        float total = red[0];
        __syncthreads();
        float invx = 1.f / nx[b];
        float mx = -1e30f;
        for (int m = t; m < 2048; m += 256) {
            long long i = (long long)b * 2048 + m;
            float d = simdot_p[i] + simdot_p[524288 + i] + simdot_p[1048576 + i];
            mx = fmaxf(mx, d * invx / nm[m]);
        }
        red[t] = mx; __syncthreads();
        for (int s = 128; s; s >>= 1) { if (t < s) red[t] = fmaxf(red[t], red[t + s]); __syncthreads(); }
        if (t == 0) sur[b] = (total == 0.f) ? 1.f : 1.f - red[0];
        return;
    }
    int ms = bid & 7, h = (bid >> 3) & 7, qt = bid >> 6;
    int q0 = qt * 64, m0 = ms * 256;
    int S = bid & 63;
    int w = t >> 6, l = t & 63;
    short* Kl = smem;            // [128][40]
    short* Pl = smem + 5120;     // [64][264]
    // Q fragment straight from global (L2-hot)
    short8 af = *(const short8*)(qkv_bf + (q0 + w * 16 + (l & 15)) * 768 + h * 32 + (l >> 4) * 8);
    f32x4 accL[16];
    #pragma unroll
    for (int j = 0; j < 16; j++) accL[j] = f32x4{0.f, 0.f, 0.f, 0.f};
    #pragma unroll
    for (int half = 0; half < 2; half++) {
        #pragma unroll
        for (int s = 0; s < 2; s++) {
            int seg = t + s * 256; int row = seg >> 2, off = (seg & 3) * 8;
            *(short8*)&Kl[row * 40 + off] =
                *(const short8*)(k_bf + (long long)(m0 + half * 128 + row) * 256 + h * 32 + off);
        }
        __syncthreads();
        #pragma unroll
        for (int j = 0; j < 8; j++) {
            short8 bf = *(const short8*)&Kl[(j * 16 + (l & 15)) * 40 + (l >> 4) * 8];
            accL[half * 8 + j] = __builtin_amdgcn_mfma_f32_16x16x32_bf16(af, bf, accL[half * 8 + j], 0, 0, 0);
        }
        __syncthreads();
    }
    int r4 = (l >> 4) * 4;
    float mloc[4], lsum[4];
    #pragma unroll
    for (int r = 0; r < 4; r++) {
        float mx = -1e30f;
        #pragma unroll
        for (int j = 0; j < 16; j++) mx = fmaxf(mx, accL[j][r] * SCALE_F);
        #pragma unroll
        for (int msk = 1; msk < 16; msk <<= 1) mx = fmaxf(mx, __shfl_xor(mx, msk, 64));
        mloc[r] = mx;
    }
    #pragma unroll
    for (int j = 0; j < 16; j++)
        #pragma unroll
        for (int r = 0; r < 4; r++)
            accL[j][r] = __expf(accL[j][r] * SCALE_F - mloc[r]);
    #pragma unroll
    for (int r = 0; r < 4; r++) {
        float ls = 0.f;
        #pragma unroll
        for (int j = 0; j < 16; j++) ls += accL[j][r];
        #pragma unroll
        for (int msk = 1; msk < 16; msk <<= 1) ls += __shfl_xor(ls, msk, 64);
        lsum[r] = ls;
    }
    if ((l & 15) == 0) {
        #pragma unroll
        for (int r = 0; r < 4; r++) {
            int gq = q0 + w * 16 + r4 + r;
            mpart[S * 256 + gq] = mloc[r];
            lpart[S * 256 + gq] = lsum[r];
        }
    }
    #pragma unroll
    for (int j = 0; j < 16; j++)
        #pragma unroll
        for (int r = 0; r < 4; r++)
            Pl[(w * 16 + r4 + r) * 264 + j * 16 + (l & 15)] = tobf(accL[j][r]);
    __syncthreads();
    f32x4 accP[2] = {{0.f,0.f,0.f,0.f},{0.f,0.f,0.f,0.f}};
    #pragma unroll
    for (int ks = 0; ks < 8; ks++) {
        short8 pa = *(const short8*)&Pl[(w * 16 + (l & 15)) * 264 + ks * 32 + (l >> 4) * 8];
        #pragma unroll
        for (int df = 0; df < 2; df++) {
            short8 vb = *(const short8*)(vt_bf + (long long)(h * 32 + df * 16 + (l & 15)) * 2048
                                         + m0 + ks * 32 + (l >> 4) * 8);
            accP[df] = __builtin_amdgcn_mfma_f32_16x16x32_bf16(pa, vb, accP[df], 0, 0, 0);
        }
    }
    #pragma unroll
    for (int df = 0; df < 2; df++)
        #pragma unroll
        for (int r = 0; r < 4; r++) {
            int gq = q0 + w * 16 + r4 + r;
            pvpart[((long long)S * 256 + gq) * 32 + df * 16 + (l & 15)] = accP[df][r];
        }
}

// ---------- 3. attn-out GEMM with inline combine (+ accept scan block) ----------
__global__ __launch_bounds__(256) void attn_gemm_k(
    const short* __restrict__ qkv_bf, const float* __restrict__ mpart,
    const float* __restrict__ lpart, const float* __restrict__ pvpart,
    const short* __restrict__ outw_bf, float* __restrict__ attn_part,
    const float* __restrict__ sur, const int* __restrict__ ptr, int* __restrict__ inv)
{
    __shared__ float ws_n[64][8];
    __shared__ float es_n[64];
    __shared__ short Al[2560];
    __shared__ short Bl[2560];
    int j = blockIdx.x, t = threadIdx.x;
    if (j >= 128) {             // accept scan (closed form + ballot prefix)
        int* ired = (int*)ws_n;
        for (int m = t; m < 2048; m += 256) inv[m] = -1;
        float s = sur[t];
        int p0 = ptr[0];
        int thresh = 2048 - p0;
        bool cond = (t < thresh) || (s > 0.5f);
        unsigned long long ball = __ballot(cond);
        int lane = t & 63, wv = t >> 6;
        if (lane == 0) ired[wv] = __popcll(ball);
        __syncthreads();
        int off = 0;
        for (int i = 0; i < wv; i++) off += ired[i];
        int rank = off + __popcll(ball & ((1ULL << lane) - 1ULL));
        if (cond) inv[(p0 + rank) & 2047] = t;
        return;
    }
    int h = j >> 4, r = j & 15, bx = r & 3, by = r >> 2;
    int b0 = by * 64, c0 = bx * 64;
    #pragma unroll
    for (int p = 0; p < 8; p++) {
        int rl = p * 8 + (t >> 5);
        int lane32 = t & 31;
        int b = b0 + rl;
        float q = frombf(qkv_bf[b * 768 + h * 32 + lane32]);
        float k = frombf(qkv_bf[b * 768 + 256 + h * 32 + lane32]);
        float prod = q * k;
        #pragma unroll
        for (int m = 16; m; m >>= 1) prod += __shfl_xor(prod, m, 64);
        float sl = prod * SCALE_F;
        if (lane32 < 8) {
            int S = h * 8 + lane32;
            float msv = mpart[S * 256 + b];
            float lpv = lpart[S * 256 + b];
            float mx = msv;
            #pragma unroll
            for (int m = 4; m; m >>= 1) mx = fmaxf(mx, __shfl_xor(mx, m, 64));
            float Mf = fmaxf(mx, sl);
            float wgt = __expf(msv - Mf);
            float suml = wgt * lpv;
            #pragma unroll
            for (int m = 4; m; m >>= 1) suml += __shfl_xor(suml, m, 64);
            float Es = __expf(sl - Mf);
            float Ls = suml + Es;
            ws_n[rl][lane32] = wgt / Ls;
            if (lane32 == 0) es_n[rl] = Es / Ls;
        }
    }
    __syncthreads();
    {
        int rl = t >> 2, cg = (t & 3) * 8;
        int b = b0 + rl;
        short8 vs8 = *(const short8*)(qkv_bf + b * 768 + 512 + h * 32 + cg);
        float es = es_n[rl];
        float a8[8];
        #pragma unroll
        for (int d = 0; d < 8; d++) a8[d] = es * frombf(vs8[d]);
        #pragma unroll
        for (int s = 0; s < 8; s++) {
            float wn = ws_n[rl][s];
            const float* pvb = pvpart + ((long long)(h * 8 + s) * 256 + b) * 32 + cg;
            float4 p0 = *(const float4*)pvb;
            float4 p1 = *(const float4*)(pvb + 4);
            a8[0] += wn * p0.x; a8[1] += wn * p0.y; a8[2] += wn * p0.z; a8[3] += wn * p0.w;
            a8[4] += wn * p1.x; a8[5] += wn * p1.y; a8[6] += wn * p1.z; a8[7] += wn * p1.w;
        }
        short8 o = {tobf(a8[0]), tobf(a8[1]), tobf(a8[2]), tobf(a8[3]),
                    tobf(a8[4]), tobf(a8[5]), tobf(a8[6]), tobf(a8[7])};
        *(short8*)&Al[rl * 40 + cg] = o;
        *(short8*)&Bl[rl * 40 + cg] = *(const short8*)(outw_bf + (long long)(c0 + rl) * 256 + h * 32 + cg);
    }
    __syncthreads();
    int w = t >> 6, l = t & 63;
    short8 af = *(const short8*)&Al[(w * 16 + (l & 15)) * 40 + (l >> 4) * 8];
    f32x4 acc[4] = {{0.f,0.f,0.f,0.f},{0.f,0.f,0.f,0.f},{0.f,0.f,0.f,0.f},{0.f,0.f,0.f,0.f}};
    #pragma unroll
    for (int j4 = 0; j4 < 4; j4++) {
        short8 bf = *(const short8*)&Bl[(j4 * 16 + (l & 15)) * 40 + (l >> 4) * 8];
        acc[j4] = __builtin_amdgcn_mfma_f32_16x16x32_bf16(af, bf, acc[j4], 0, 0, 0);
    }
    int lc = l & 15, lr = (l >> 4) * 4;
    #pragma unroll
    for (int j4 = 0; j4 < 4; j4++) {
        int col = c0 + j4 * 16 + lc;
        #pragma unroll
        for (int rr = 0; rr < 4; rr++) {
            int row = b0 + w * 16 + lr + rr;
            attn_part[(long long)h * 65536 + row * 256 + col] = acc[j4][rr];
        }
    }
}

// ---------- 4. ff1 GEMM with inline LayerNorm A-staging ----------
__global__ __launch_bounds__(256) void ff1_ln_k(
    const float* __restrict__ attn_part, const float* __restrict__ out_b,
    const float* __restrict__ src, const float* __restrict__ g1,
    const float* __restrict__ be1, const short* __restrict__ w1_bf,
    const float* __restrict__ b1, float* __restrict__ hbuf, short* __restrict__ ff1_bf)
{
    __shared__ short Afull[64 * 264];
    __shared__ short Bl[2560];
    int bx = blockIdx.x, by = blockIdx.y;
    int t = threadIdx.x, w = t >> 6, l = t & 63;
    #pragma unroll
    for (int p = 0; p < 16; p++) {
        int rl = p * 4 + w;
        int r = by * 64 + rl;
        int c = l * 4;
        float4 x = *(const float4*)(out_b + c);
        float4 sv = *(const float4*)(src + (long long)r * 256 + c);
        x.x += sv.x; x.y += sv.y; x.z += sv.z; x.w += sv.w;
        #pragma unroll
        for (int pp = 0; pp < 8; pp++) {
            float4 a = *(const float4*)(attn_part + (long long)pp * 65536 + r * 256 + c);
            x.x += a.x; x.y += a.y; x.z += a.z; x.w += a.w;
        }
        float s = x.x + x.y + x.z + x.w;
        #pragma unroll
        for (int m = 32; m; m >>= 1) s += __shfl_xor(s, m, 64);
        float mean = s * (1.f / 256.f);
        float4 cv = {x.x - mean, x.y - mean, x.z - mean, x.w - mean};
        float ss = cv.x * cv.x + cv.y * cv.y + cv.z * cv.z + cv.w * cv.w;
        #pragma unroll
        for (int m = 32; m; m >>= 1) ss += __shfl_xor(ss, m, 64);
        float rstd = rsqrtf(ss * (1.f / 256.f) + 1e-5f);
        float4 gg = *(const float4*)(g1 + c);
        float4 bb = *(const float4*)(be1 + c);
        float4 y = {cv.x * rstd * gg.x + bb.x, cv.y * rstd * gg.y + bb.y,
                    cv.z * rstd * gg.z + bb.z, cv.w * rstd * gg.w + bb.w};
        if (bx == 0) *(float4*)(hbuf + (long long)r * 256 + c) = y;
        short4v yb = {tobf(y.x), tobf(y.y), tobf(y.z), tobf(y.w)};
        *(short4v*)&Afull[rl * 264 + c] = yb;
    }
    __syncthreads();
    int c0 = bx * 64;
    int srow = t >> 2, scol = (t & 3) * 8;
    f32x4 acc[4] = {{0.f,0.f,0.f,0.f},{0.f,0.f,0.f,0.f},{0.f,0.f,0.f,0.f},{0.f,0.f,0.f,0.f}};
    for (int kk = 0; kk < 256; kk += 32) {
        *(short8*)&Bl[srow * 40 + scol] = *(const short8*)(w1_bf + (long long)(c0 + srow) * 256 + kk + scol);
        __syncthreads();
        short8 af = *(const short8*)&Afull[(w * 16 + (l & 15)) * 264 + kk + (l >> 4) * 8];
        #pragma unroll
        for (int j = 0; j < 4; j++) {
            short8 bf = *(const short8*)&Bl[(j * 16 + (l & 15)) * 40 + (l >> 4) * 8];
            acc[j] = __builtin_amdgcn_mfma_f32_16x16x32_bf16(af, bf, acc[j], 0, 0, 0);
        }
        __syncthreads();
    }
    int lc = l & 15, lr = (l >> 4) * 4;
    #pragma unroll
    for (int j = 0; j < 4; j++) {
        int col = c0 + j * 16 + lc;
        float bv = b1[col];
        #pragma unroll
        for (int r = 0; r < 4; r++) {
            int row = by * 64 + w * 16 + lr + r;
            float v = fmaxf(acc[j][r] + bv, 0.f);
            ff1_bf[(long long)row * 1024 + col] = tobf(v);
        }
    }
}

// ---------- shared bf16 tile GEMM (k-split) for ff2 ----------
__device__ __forceinline__ void gemm_tile(short* lds,
    const short* __restrict__ A, int lda, const short* __restrict__ B, int ldb,
    float* Cf, int ldc, long long coff, int Klen, int kbeg, int bx, int by)
{
    short* Al = lds;
    short* Bl = lds + 2560;
    int t = threadIdx.x, w = t >> 6, l = t & 63;
    int r0 = by * 64, c0 = bx * 64;
    int srow = t >> 2, scol = (t & 3) * 8;
    f32x4 acc[4] = {{0.f,0.f,0.f,0.f},{0.f,0.f,0.f,0.f},{0.f,0.f,0.f,0.f},{0.f,0.f,0.f,0.f}};
    for (int kk = 0; kk < Klen; kk += 32) {
        int k0 = kbeg + kk;
        *(short8*)&Al[srow * 40 + scol] = *(const short8*)(A + (long long)(r0 + srow) * lda + k0 + scol);
        *(short8*)&Bl[srow * 40 + scol] = *(const short8*)(B + (long long)(c0 + srow) * ldb + k0 + scol);
        __syncthreads();
        short8 af = *(const short8*)&Al[(w * 16 + (l & 15)) * 40 + (l >> 4) * 8];
        #pragma unroll
        for (int j = 0; j < 4; j++) {
            short8 bf = *(const short8*)&Bl[(j * 16 + (l & 15)) * 40 + (l >> 4) * 8];
            acc[j] = __builtin_amdgcn_mfma_f32_16x16x32_bf16(af, bf, acc[j], 0, 0, 0);
        }
        __syncthreads();
    }
    int lc = l & 15, lr = (l >> 4) * 4;
    #pragma unroll
    for (int j = 0; j < 4; j++) {
        int col = c0 + j * 16 + lc;
        #pragma unroll
        for (int r = 0; r < 4; r++) {
            int row = r0 + w * 16 + lr + r;
            Cf[coff + (long long)row * ldc + col] = acc[j][r];
        }
    }
}

// ---------- 5. ff2 GEMM (k-split 8) || memory update ----------
__global__ __launch_bounds__(256) void ff2_mem_k(
    const short* __restrict__ ff1_bf, const short* __restrict__ w2_bf,
    float* __restrict__ ff2_part,
    const float* __restrict__ memory, const float* __restrict__ momentum,
    const float* __restrict__ scores, const float* __restrict__ hbuf,
    const float* __restrict__ sur, const int* __restrict__ inv,
    float* __restrict__ mem_o, float* __restrict__ mom_o, float* __restrict__ sc_o)
{
    __shared__ short lds[5120];
    int j = blockIdx.x, t = threadIdx.x;
    if (j < 128) {
        int ks = j >> 4, r = j & 15;
        gemm_tile(lds, ff1_bf, 1024, w2_bf, 1024, ff2_part, 256,
                  (long long)ks * 65536, 128, ks * 128, r & 3, r >> 2);
        return;
    }
    int w = t >> 6, l = t & 63;
    int m = (j - 128) * 4 + w;
    int b = inv[m];
    long long o = (long long)m * 256 + l * 4;
    float4 xm = *(const float4*)(memory + o);
    float4 mo = *(const float4*)(momentum + o);
    if (b >= 0) {
        float4 hb = *(const float4*)(hbuf + (long long)b * 256 + l * 4);
        float4 nmom = {0.9f * mo.x + 0.1f * (hb.x - xm.x), 0.9f * mo.y + 0.1f * (hb.y - xm.y),
                       0.9f * mo.z + 0.1f * (hb.z - xm.z), 0.9f * mo.w + 0.1f * (hb.w - xm.w)};
        float4 nm4 = {xm.x + 0.1f * nmom.x, xm.y + 0.1f * nmom.y,
                      xm.z + 0.1f * nmom.z, xm.w + 0.1f * nmom.w};
        *(float4*)(mem_o + o) = nm4;
        *(float4*)(mom_o + o) = nmom;
        if (l == 0) sc_o[m] = sur[b];
    } else {
        *(float4*)(mem_o + o) = xm;
        *(float4*)(mom_o + o) = mo;
        if (l == 0) sc_o[m] = scores[m];
    }
}

// ---------- 6. final LayerNorm ----------
__global__ __launch_bounds__(256) void ln2_k(
    const float* __restrict__ ff2_part, const float* __restrict__ b2,
    const float* __restrict__ hbuf, const float* __restrict__ g2,
    const float* __restrict__ be2, float* __restrict__ out_main)
{
    int t = threadIdx.x, w = t >> 6, l = t & 63;
    int r = blockIdx.x * 4 + w;
    int c = l * 4;
    float4 x = *(const float4*)(b2 + c);
    float4 hv = *(const float4*)(hbuf + (long long)r * 256 + c);
    x.x += hv.x; x.y += hv.y; x.z += hv.z; x.w += hv.w;
    #pragma unroll
    for (int pp = 0; pp < 8; pp++) {
        float4 a = *(const float4*)(ff2_part + (long long)pp * 65536 + r * 256 + c);
        x.x += a.x; x.y += a.y; x.z += a.z; x.w += a.w;
    }
    float s = x.x + x.y + x.z + x.w;
    #pragma unroll
    for (int m = 32; m; m >>= 1) s += __shfl_xor(s, m, 64);
    float mean = s * (1.f / 256.f);
    float4 cv = {x.x - mean, x.y - mean, x.z - mean, x.w - mean};
    float ss = cv.x * cv.x + cv.y * cv.y + cv.z * cv.z + cv.w * cv.w;
    #pragma unroll
    for (int m = 32; m; m >>= 1) ss += __shfl_xor(ss, m, 64);
    float rstd = rsqrtf(ss * (1.f / 256.f) + 1e-5f);
    float4 gg = *(const float4*)(g2 + c);
    float4 bb = *(const float4*)(be2 + c);
    float4 y = {cv.x * rstd * gg.x + bb.x, cv.y * rstd * gg.y + bb.y,
                cv.z * rstd * gg.z + bb.z, cv.w * rstd * gg.w + bb.w};
    *(float4*)(out_main + (long long)r * 256 + c) = y;
}

extern "C" void kernel_launch(void* const* d_in, const int* in_sizes, int n_in,
                              void* d_out, int out_size, void* d_ws, size_t ws_size,
                              hipStream_t stream)
{
    const float* src      = (const float*)d_in[0];
    const float* memory   = (const float*)d_in[1];
    const float* momentum = (const float*)d_in[2];
    const float* scores   = (const float*)d_in[3];
    const float* ipw      = (const float*)d_in[4];
    const float* ipb      = (const float*)d_in[5];
    const float* out_w    = (const float*)d_in[6];
    const float* out_b    = (const float*)d_in[7];
    const float* w1       = (const float*)d_in[8];
    const float* b1       = (const float*)d_in[9];
    const float* w2       = (const float*)d_in[10];
    const float* b2       = (const float*)d_in[11];
    const float* g1       = (const float*)d_in[12];
    const float* be1      = (const float*)d_in[13];
    const float* g2       = (const float*)d_in[14];
    const float* be2      = (const float*)d_in[15];
    const int*   ptr      = (const int*)d_in[16];

    float* o = (float*)d_out;
    float* out_main = o;
    float* mem_o = o + 65536;
    float* mom_o = mem_o + 524288;
    float* sc_o  = mom_o + 524288;

    char* wp = (char*)d_ws;
    auto alloc = [&](size_t n) { void* q = (void*)wp; wp += (n + 255) & ~(size_t)255; return q; };
    short* qkv_bf   = (short*)alloc(393216);     // [256][768]
    short* k_bf     = (short*)alloc(1048576);    // [2048][256]
    short* vt_bf    = (short*)alloc(1048576);    // [256][2048]
    short* outw_bf  = (short*)alloc(131072);     // [256][256]
    short* w1_bf    = (short*)alloc(524288);     // [1024][256]
    short* w2_bf    = (short*)alloc(524288);     // [256][1024]
    short* ff1_bf   = (short*)alloc(524288);     // [256][1024]
    float* simdot_p = (float*)alloc(6291456);    // [3][256][2048]
    float* pvpart   = (float*)alloc(2097152);    // [64 S][256 q][32 d]
    float* mpart    = (float*)alloc(65536);      // [64 S][256 q]
    float* lpart    = (float*)alloc(65536);
    float* attn_part= (float*)alloc(2097152);    // [8][256][256]
    float* ff2_part = (float*)alloc(2097152);    // [8][256][256]
    float* hbuf     = (float*)alloc(262144);     // [256][256] f32
    float* nx       = (float*)alloc(1024);
    float* nm       = (float*)alloc(8192);
    float* nm2      = (float*)alloc(8192);
    float* sur      = (float*)alloc(1024);
    int*   inv      = (int*)alloc(8192);

    // 1. projections + conversions + norms
    proj_k<<<868, 256, 0, stream>>>(src, memory, ipw, ipb, out_w, w1, w2,
        simdot_p, qkv_bf, k_bf, vt_bf, outw_bf, w1_bf, w2_bf, nx, nm, nm2);
    // 2. flash attention || surprise
    flash_sur_k<<<512, 256, 0, stream>>>(qkv_bf, k_bf, vt_bf, pvpart, mpart, lpart,
        simdot_p, nx, nm, nm2, sur);
    // 3. attn-out GEMM (inline combine) + accept scan
    attn_gemm_k<<<129, 256, 0, stream>>>(qkv_bf, mpart, lpart, pvpart, outw_bf,
        attn_part, sur, ptr, inv);
    // 4. ff1 GEMM (inline LN1; bx==0 writes hbuf)
    ff1_ln_k<<<dim3(16, 4), 256, 0, stream>>>(attn_part, out_b, src, g1, be1,
        w1_bf, b1, hbuf, ff1_bf);
    // 5. ff2 GEMM || memory update
    ff2_mem_k<<<640, 256, 0, stream>>>(ff1_bf, w2_bf, ff2_part,
        memory, momentum, scores, hbuf, sur, inv, mem_o, mom_o, sc_o);
    // 6. final LN
    ln2_k<<<64, 256, 0, stream>>>(ff2_part, b2, hbuf, g2, be2, out_main);
}

// Round 10
// 137.663 us; speedup vs baseline: 4.4033x; 1.0601x over previous
//
#include <hip/hip_runtime.h>
#include <math.h>

// B=256, D=256, H=8, FF=1024, M=2048
#define SCALE_F 0.17677669529663687f

typedef __attribute__((ext_vector_type(8))) short short8;
typedef __attribute__((ext_vector_type(4))) short short4v;
typedef __attribute__((ext_vector_type(4))) float f32x4;

__device__ inline short tobf(float x) {
    unsigned u = __float_as_uint(x);
    unsigned r = (u + 0x7FFFu + ((u >> 16) & 1u)) >> 16;
    return (short)r;
}
__device__ inline float frombf(short s) {
    return __uint_as_float(((unsigned)(unsigned short)s) << 16);
}

// convert 8 f32 -> bf16
__device__ __forceinline__ short8 cv8(const float* __restrict__ p) {
    float4 a = *(const float4*)p, b = *(const float4*)(p + 4);
    short8 o = {tobf(a.x), tobf(a.y), tobf(a.z), tobf(a.w),
                tobf(b.x), tobf(b.y), tobf(b.z), tobf(b.w)};
    return o;
}

// ---------- staged-convert GEMM body: C = A_f32(cv) @ B_f32(cv)^T, K=256 ----------
__device__ __forceinline__ void gemm_cv(short* lds,
    const float* __restrict__ A, int lda,
    const float* __restrict__ B, int ldb,
    float* Cf, short* Cb, int ldc, const float* bias, int transC, int bx, int by)
{
    short* Al = lds;           // [64][40]
    short* Bl = lds + 2560;    // [64][40]
    int t = threadIdx.x, w = t >> 6, l = t & 63;
    int r0 = by * 64, c0 = bx * 64;
    int srow = t >> 2, scol = (t & 3) * 8;
    f32x4 acc[4] = {{0.f,0.f,0.f,0.f},{0.f,0.f,0.f,0.f},{0.f,0.f,0.f,0.f},{0.f,0.f,0.f,0.f}};
    for (int kk = 0; kk < 256; kk += 32) {
        *(short8*)&Al[srow * 40 + scol] = cv8(A + (long long)(r0 + srow) * lda + kk + scol);
        *(short8*)&Bl[srow * 40 + scol] = cv8(B + (long long)(c0 + srow) * ldb + kk + scol);
        __syncthreads();
        short8 af = *(const short8*)&Al[(w * 16 + (l & 15)) * 40 + (l >> 4) * 8];
        #pragma unroll
        for (int j = 0; j < 4; j++) {
            short8 bf = *(const short8*)&Bl[(j * 16 + (l & 15)) * 40 + (l >> 4) * 8];
            acc[j] = __builtin_amdgcn_mfma_f32_16x16x32_bf16(af, bf, acc[j], 0, 0, 0);
        }
        __syncthreads();
    }
    int lc = l & 15, lr = (l >> 4) * 4;
    #pragma unroll
    for (int j = 0; j < 4; j++) {
        int col = c0 + j * 16 + lc;
        float bv = bias ? bias[col] : 0.f;
        #pragma unroll
        for (int r = 0; r < 4; r++) {
            int row = r0 + w * 16 + lr + r;
            float v = acc[j][r] + bv;
            long long idx = transC ? (long long)col * ldc + row : (long long)row * ldc + col;
            if (Cf) Cf[idx] = v;
            else    Cb[idx] = tobf(v);
        }
    }
}

// ---------- 1. projections + conversions + norms, one launch (612 blocks) ----------
// 0..127   simdot = src_bf @ memory_bf^T (plain bf16; margin to 0.5 thr is ~16 sigma)
// 128..255 k_bf = mem @ Wk^T + bk
// 256..383 vt_bf = (mem @ Wv^T + bv)^T
// 384..431 qkv_bf = src @ ipw^T + ipb
// 432..467 row norms (64 rows/block)
// 468..611 weight cvt (outw|w1|w2, 4096 elems/block)
__global__ __launch_bounds__(256) void proj_k(
    const float* __restrict__ src, const float* __restrict__ memory,
    const float* __restrict__ ipw, const float* __restrict__ ipb,
    const float* __restrict__ out_w, const float* __restrict__ w1, const float* __restrict__ w2,
    float* __restrict__ simdot, short* __restrict__ qkv_bf,
    short* __restrict__ k_bf, short* __restrict__ vt_bf,
    short* __restrict__ outw_bf, short* __restrict__ w1_bf, short* __restrict__ w2_bf,
    float* __restrict__ nx, float* __restrict__ nm, float* __restrict__ nm2)
{
    __shared__ short lds[5120];
    int bid = blockIdx.x, t = threadIdx.x, w = t >> 6, l = t & 63;
    if (bid < 128) {
        gemm_cv(lds, src, 256, memory, 256,
                simdot, nullptr, 2048, nullptr, 0, bid & 31, bid >> 5);
    } else if (bid < 256) {
        int r = bid - 128;
        gemm_cv(lds, memory, 256, ipw + 65536, 256,
                nullptr, k_bf, 256, ipb + 256, 0, r & 3, r >> 2);
    } else if (bid < 384) {
        int r = bid - 256;
        gemm_cv(lds, memory, 256, ipw + 131072, 256,
                nullptr, vt_bf, 2048, ipb + 512, 1, r & 3, r >> 2);
    } else if (bid < 432) {
        int r = bid - 384;
        gemm_cv(lds, src, 256, ipw, 256,
                nullptr, qkv_bf, 768, ipb, 0, r % 12, r / 12);
    } else if (bid < 468) {
        int nb = bid - 432;
        #pragma unroll
        for (int i = 0; i < 16; i++) {
            int r = nb * 64 + i * 4 + w;
            bool issrc = r < 256;
            int rr = issrc ? r : r - 256;
            const float* rowp = issrc ? src + (long long)rr * 256 : memory + (long long)rr * 256;
            float4 x = *(const float4*)(rowp + l * 4);
            float ss = x.x * x.x + x.y * x.y + x.z * x.z + x.w * x.w;
            #pragma unroll
            for (int m = 32; m; m >>= 1) ss += __shfl_xor(ss, m, 64);
            if (l == 0) {
                if (issrc) nx[rr] = fmaxf(sqrtf(ss), 1e-8f);
                else { nm[rr] = fmaxf(sqrtf(ss), 1e-8f); nm2[rr] = ss; }
            }
        }
    } else {
        long long base = (long long)(bid - 468) * 4096 + t * 8;
        #pragma unroll
        for (int rep = 0; rep < 2; rep++) {
            long long e = base + rep * 2048;
            const float* sp; short* dp; long long off;
            if (e < 65536)       { sp = out_w; dp = outw_bf; off = e; }
            else if (e < 327680) { sp = w1;    dp = w1_bf;   off = e - 65536; }
            else                 { sp = w2;    dp = w2_bf;   off = e - 327680; }
            *(short8*)&dp[off] = cv8(sp + off);
        }
    }
}

// ---------- 2. flash attention (split-m, 44KB LDS) || surprise ----------
__global__ __launch_bounds__(256) void flash_sur_k(
    const short* __restrict__ qkv_bf, const short* __restrict__ k_bf,
    const short* __restrict__ vt_bf,
    float* __restrict__ pvpart, float* __restrict__ mpart, float* __restrict__ lpart,
    const float* __restrict__ simdot, const float* __restrict__ nx,
    const float* __restrict__ nm, const float* __restrict__ nm2, float* __restrict__ sur)
{
    __shared__ __align__(16) short smem[22016];   // Kl [128][40] | Pl [64][264]
    int bid = blockIdx.x, t = threadIdx.x;
    if (bid >= 256) {           // surprise
        float* red = (float*)smem;
        int b = bid - 256;
        float tot = 0.f;
        for (int m = t; m < 2048; m += 256) tot += nm2[m];
        red[t] = tot; __syncthreads();
        for (int s = 128; s; s >>= 1) { if (t < s) red[t] += red[t + s]; __syncthreads(); }
        float total = red[0];
        __syncthreads();
        float invx = 1.f / nx[b];
        float mx = -1e30f;
        for (int m = t; m < 2048; m += 256) {
            float d = simdot[(long long)b * 2048 + m];
            mx = fmaxf(mx, d * invx / nm[m]);
        }
        red[t] = mx; __syncthreads();
        for (int s = 128; s; s >>= 1) { if (t < s) red[t] = fmaxf(red[t], red[t + s]); __syncthreads(); }
        if (t == 0) sur[b] = (total == 0.f) ? 1.f : 1.f - red[0];
        return;
    }
    int ms = bid & 7, h = (bid >> 3) & 7, qt = bid >> 6;
    int q0 = qt * 64, m0 = ms * 256;
    int S = bid & 63;
    int w = t >> 6, l = t & 63;
    short* Kl = smem;            // [128][40]
    short* Pl = smem + 5120;     // [64][264]
    short8 af = *(const short8*)(qkv_bf + (q0 + w * 16 + (l & 15)) * 768 + h * 32 + (l >> 4) * 8);
    f32x4 accL[16];
    #pragma unroll
    for (int j = 0; j < 16; j++) accL[j] = f32x4{0.f, 0.f, 0.f, 0.f};
    #pragma unroll
    for (int half = 0; half < 2; half++) {
        #pragma unroll
        for (int s = 0; s < 2; s++) {
            int seg = t + s * 256; int row = seg >> 2, off = (seg & 3) * 8;
            *(short8*)&Kl[row * 40 + off] =
                *(const short8*)(k_bf + (long long)(m0 + half * 128 + row) * 256 + h * 32 + off);
        }
        __syncthreads();
        #pragma unroll
        for (int j = 0; j < 8; j++) {
            short8 bf = *(const short8*)&Kl[(j * 16 + (l & 15)) * 40 + (l >> 4) * 8];
            accL[half * 8 + j] = __builtin_amdgcn_mfma_f32_16x16x32_bf16(af, bf, accL[half * 8 + j], 0, 0, 0);
        }
        __syncthreads();
    }
    int r4 = (l >> 4) * 4;
    float mloc[4], lsum[4];
    #pragma unroll
    for (int r = 0; r < 4; r++) {
        float mx = -1e30f;
        #pragma unroll
        for (int j = 0; j < 16; j++) mx = fmaxf(mx, accL[j][r] * SCALE_F);
        #pragma unroll
        for (int msk = 1; msk < 16; msk <<= 1) mx = fmaxf(mx, __shfl_xor(mx, msk, 64));
        mloc[r] = mx;
    }
    #pragma unroll
    for (int j = 0; j < 16; j++)
        #pragma unroll
        for (int r = 0; r < 4; r++)
            accL[j][r] = __expf(accL[j][r] * SCALE_F - mloc[r]);
    #pragma unroll
    for (int r = 0; r < 4; r++) {
        float ls = 0.f;
        #pragma unroll
        for (int j = 0; j < 16; j++) ls += accL[j][r];
        #pragma unroll
        for (int msk = 1; msk < 16; msk <<= 1) ls += __shfl_xor(ls, msk, 64);
        lsum[r] = ls;
    }
    if ((l & 15) == 0) {
        #pragma unroll
        for (int r = 0; r < 4; r++) {
            int gq = q0 + w * 16 + r4 + r;
            mpart[S * 256 + gq] = mloc[r];
            lpart[S * 256 + gq] = lsum[r];
        }
    }
    #pragma unroll
    for (int j = 0; j < 16; j++)
        #pragma unroll
        for (int r = 0; r < 4; r++)
            Pl[(w * 16 + r4 + r) * 264 + j * 16 + (l & 15)] = tobf(accL[j][r]);
    __syncthreads();
    f32x4 accP[2] = {{0.f,0.f,0.f,0.f},{0.f,0.f,0.f,0.f}};
    #pragma unroll
    for (int ks = 0; ks < 8; ks++) {
        short8 pa = *(const short8*)&Pl[(w * 16 + (l & 15)) * 264 + ks * 32 + (l >> 4) * 8];
        #pragma unroll
        for (int df = 0; df < 2; df++) {
            short8 vb = *(const short8*)(vt_bf + (long long)(h * 32 + df * 16 + (l & 15)) * 2048
                                         + m0 + ks * 32 + (l >> 4) * 8);
            accP[df] = __builtin_amdgcn_mfma_f32_16x16x32_bf16(pa, vb, accP[df], 0, 0, 0);
        }
    }
    #pragma unroll
    for (int df = 0; df < 2; df++)
        #pragma unroll
        for (int r = 0; r < 4; r++) {
            int gq = q0 + w * 16 + r4 + r;
            pvpart[((long long)S * 256 + gq) * 32 + df * 16 + (l & 15)] = accP[df][r];
        }
}

// ---------- 3. attn-out GEMM with inline combine (+ accept scan block) ----------
__global__ __launch_bounds__(256) void attn_gemm_k(
    const short* __restrict__ qkv_bf, const float* __restrict__ mpart,
    const float* __restrict__ lpart, const float* __restrict__ pvpart,
    const short* __restrict__ outw_bf, float* __restrict__ attn_part,
    const float* __restrict__ sur, const int* __restrict__ ptr, int* __restrict__ inv)
{
    __shared__ float ws_n[64][8];
    __shared__ float es_n[64];
    __shared__ short Al[2560];
    __shared__ short Bl[2560];
    int j = blockIdx.x, t = threadIdx.x;
    if (j >= 128) {             // accept scan (closed form + ballot prefix)
        int* ired = (int*)ws_n;
        for (int m = t; m < 2048; m += 256) inv[m] = -1;
        float s = sur[t];
        int p0 = ptr[0];
        int thresh = 2048 - p0;
        bool cond = (t < thresh) || (s > 0.5f);
        unsigned long long ball = __ballot(cond);
        int lane = t & 63, wv = t >> 6;
        if (lane == 0) ired[wv] = __popcll(ball);
        __syncthreads();
        int off = 0;
        for (int i = 0; i < wv; i++) off += ired[i];
        int rank = off + __popcll(ball & ((1ULL << lane) - 1ULL));
        if (cond) inv[(p0 + rank) & 2047] = t;
        return;
    }
    int h = j >> 4, r = j & 15, bx = r & 3, by = r >> 2;
    int b0 = by * 64, c0 = bx * 64;
    #pragma unroll
    for (int p = 0; p < 8; p++) {
        int rl = p * 8 + (t >> 5);
        int lane32 = t & 31;
        int b = b0 + rl;
        float q = frombf(qkv_bf[b * 768 + h * 32 + lane32]);
        float k = frombf(qkv_bf[b * 768 + 256 + h * 32 + lane32]);
        float prod = q * k;
        #pragma unroll
        for (int m = 16; m; m >>= 1) prod += __shfl_xor(prod, m, 64);
        float sl = prod * SCALE_F;
        if (lane32 < 8) {
            int S = h * 8 + lane32;
            float msv = mpart[S * 256 + b];
            float lpv = lpart[S * 256 + b];
            float mx = msv;
            #pragma unroll
            for (int m = 4; m; m >>= 1) mx = fmaxf(mx, __shfl_xor(mx, m, 64));
            float Mf = fmaxf(mx, sl);
            float wgt = __expf(msv - Mf);
            float suml = wgt * lpv;
            #pragma unroll
            for (int m = 4; m; m >>= 1) suml += __shfl_xor(suml, m, 64);
            float Es = __expf(sl - Mf);
            float Ls = suml + Es;
            ws_n[rl][lane32] = wgt / Ls;
            if (lane32 == 0) es_n[rl] = Es / Ls;
        }
    }
    __syncthreads();
    {
        int rl = t >> 2, cg = (t & 3) * 8;
        int b = b0 + rl;
        short8 vs8 = *(const short8*)(qkv_bf + b * 768 + 512 + h * 32 + cg);
        float es = es_n[rl];
        float a8[8];
        #pragma unroll
        for (int d = 0; d < 8; d++) a8[d] = es * frombf(vs8[d]);
        #pragma unroll
        for (int s = 0; s < 8; s++) {
            float wn = ws_n[rl][s];
            const float* pvb = pvpart + ((long long)(h * 8 + s) * 256 + b) * 32 + cg;
            float4 p0 = *(const float4*)pvb;
            float4 p1 = *(const float4*)(pvb + 4);
            a8[0] += wn * p0.x; a8[1] += wn * p0.y; a8[2] += wn * p0.z; a8[3] += wn * p0.w;
            a8[4] += wn * p1.x; a8[5] += wn * p1.y; a8[6] += wn * p1.z; a8[7] += wn * p1.w;
        }
        short8 o = {tobf(a8[0]), tobf(a8[1]), tobf(a8[2]), tobf(a8[3]),
                    tobf(a8[4]), tobf(a8[5]), tobf(a8[6]), tobf(a8[7])};
        *(short8*)&Al[rl * 40 + cg] = o;
        *(short8*)&Bl[rl * 40 + cg] = *(const short8*)(outw_bf + (long long)(c0 + rl) * 256 + h * 32 + cg);
    }
    __syncthreads();
    int w = t >> 6, l = t & 63;
    short8 af = *(const short8*)&Al[(w * 16 + (l & 15)) * 40 + (l >> 4) * 8];
    f32x4 acc[4] = {{0.f,0.f,0.f,0.f},{0.f,0.f,0.f,0.f},{0.f,0.f,0.f,0.f},{0.f,0.f,0.f,0.f}};
    #pragma unroll
    for (int j4 = 0; j4 < 4; j4++) {
        short8 bf = *(const short8*)&Bl[(j4 * 16 + (l & 15)) * 40 + (l >> 4) * 8];
        acc[j4] = __builtin_amdgcn_mfma_f32_16x16x32_bf16(af, bf, acc[j4], 0, 0, 0);
    }
    int lc = l & 15, lr = (l >> 4) * 4;
    #pragma unroll
    for (int j4 = 0; j4 < 4; j4++) {
        int col = c0 + j4 * 16 + lc;
        #pragma unroll
        for (int rr = 0; rr < 4; rr++) {
            int row = b0 + w * 16 + lr + rr;
            attn_part[(long long)h * 65536 + row * 256 + col] = acc[j4][rr];
        }
    }
}

// ---------- 4. ff1 GEMM with inline LayerNorm A-staging (32-row tiles, 128 blocks) ----------
__global__ __launch_bounds__(256) void ff1_ln_k(
    const float* __restrict__ attn_part, const float* __restrict__ out_b,
    const float* __restrict__ src, const float* __restrict__ g1,
    const float* __restrict__ be1, const short* __restrict__ w1_bf,
    const float* __restrict__ b1, float* __restrict__ hbuf, short* __restrict__ ff1_bf)
{
    __shared__ short Afull[32 * 264];
    __shared__ short Bl[2560];
    int bx = blockIdx.x, by = blockIdx.y;    // bx: 16 col-tiles of 64; by: 8 row-tiles of 32
    int t = threadIdx.x, w = t >> 6, l = t & 63;
    #pragma unroll
    for (int p = 0; p < 8; p++) {
        int rl = p * 4 + w;                  // 0..31
        int r = by * 32 + rl;
        int c = l * 4;
        float4 x = *(const float4*)(out_b + c);
        float4 sv = *(const float4*)(src + (long long)r * 256 + c);
        x.x += sv.x; x.y += sv.y; x.z += sv.z; x.w += sv.w;
        #pragma unroll
        for (int pp = 0; pp < 8; pp++) {
            float4 a = *(const float4*)(attn_part + (long long)pp * 65536 + r * 256 + c);
            x.x += a.x; x.y += a.y; x.z += a.z; x.w += a.w;
        }
        float s = x.x + x.y + x.z + x.w;
        #pragma unroll
        for (int m = 32; m; m >>= 1) s += __shfl_xor(s, m, 64);
        float mean = s * (1.f / 256.f);
        float4 cv = {x.x - mean, x.y - mean, x.z - mean, x.w - mean};
        float ss = cv.x * cv.x + cv.y * cv.y + cv.z * cv.z + cv.w * cv.w;
        #pragma unroll
        for (int m = 32; m; m >>= 1) ss += __shfl_xor(ss, m, 64);
        float rstd = rsqrtf(ss * (1.f / 256.f) + 1e-5f);
        float4 gg = *(const float4*)(g1 + c);
        float4 bb = *(const float4*)(be1 + c);
        float4 y = {cv.x * rstd * gg.x + bb.x, cv.y * rstd * gg.y + bb.y,
                    cv.z * rstd * gg.z + bb.z, cv.w * rstd * gg.w + bb.w};
        if (bx == 0) *(float4*)(hbuf + (long long)r * 256 + c) = y;
        short4v yb = {tobf(y.x), tobf(y.y), tobf(y.z), tobf(y.w)};
        *(short4v*)&Afull[rl * 264 + c] = yb;
    }
    __syncthreads();
    int c0 = bx * 64;
    int srow = t >> 2, scol = (t & 3) * 8;
    int wr = w & 1, wc = w >> 1;
    f32x4 acc[2] = {{0.f,0.f,0.f,0.f},{0.f,0.f,0.f,0.f}};
    for (int kk = 0; kk < 256; kk += 32) {
        *(short8*)&Bl[srow * 40 + scol] = *(const short8*)(w1_bf + (long long)(c0 + srow) * 256 + kk + scol);
        __syncthreads();
        short8 af = *(const short8*)&Afull[(wr * 16 + (l & 15)) * 264 + kk + (l >> 4) * 8];
        #pragma unroll
        for (int jj = 0; jj < 2; jj++) {
            int j = wc * 2 + jj;
            short8 bf = *(const short8*)&Bl[(j * 16 + (l & 15)) * 40 + (l >> 4) * 8];
            acc[jj] = __builtin_amdgcn_mfma_f32_16x16x32_bf16(af, bf, acc[jj], 0, 0, 0);
        }
        __syncthreads();
    }
    int lc = l & 15, lr = (l >> 4) * 4;
    #pragma unroll
    for (int jj = 0; jj < 2; jj++) {
        int col = c0 + (wc * 2 + jj) * 16 + lc;
        float bv = b1[col];
        #pragma unroll
        for (int r = 0; r < 4; r++) {
            int row = by * 32 + wr * 16 + lr + r;
            float v = fmaxf(acc[jj][r] + bv, 0.f);
            ff1_bf[(long long)row * 1024 + col] = tobf(v);
        }
    }
}

// ---------- shared bf16 tile GEMM (k-split) for ff2 ----------
__device__ __forceinline__ void gemm_tile(short* lds,
    const short* __restrict__ A, int lda, const short* __restrict__ B, int ldb,
    float* Cf, int ldc, long long coff, int Klen, int kbeg, int bx, int by)
{
    short* Al = lds;
    short* Bl = lds + 2560;
    int t = threadIdx.x, w = t >> 6, l = t & 63;
    int r0 = by * 64, c0 = bx * 64;
    int srow = t >> 2, scol = (t & 3) * 8;
    f32x4 acc[4] = {{0.f,0.f,0.f,0.f},{0.f,0.f,0.f,0.f},{0.f,0.f,0.f,0.f},{0.f,0.f,0.f,0.f}};
    for (int kk = 0; kk < Klen; kk += 32) {
        int k0 = kbeg + kk;
        *(short8*)&Al[srow * 40 + scol] = *(const short8*)(A + (long long)(r0 + srow) * lda + k0 + scol);
        *(short8*)&Bl[srow * 40 + scol] = *(const short8*)(B + (long long)(c0 + srow) * ldb + k0 + scol);
        __syncthreads();
        short8 af = *(const short8*)&Al[(w * 16 + (l & 15)) * 40 + (l >> 4) * 8];
        #pragma unroll
        for (int j = 0; j < 4; j++) {
            short8 bf = *(const short8*)&Bl[(j * 16 + (l & 15)) * 40 + (l >> 4) * 8];
            acc[j] = __builtin_amdgcn_mfma_f32_16x16x32_bf16(af, bf, acc[j], 0, 0, 0);
        }
        __syncthreads();
    }
    int lc = l & 15, lr = (l >> 4) * 4;
    #pragma unroll
    for (int j = 0; j < 4; j++) {
        int col = c0 + j * 16 + lc;
        #pragma unroll
        for (int r = 0; r < 4; r++) {
            int row = r0 + w * 16 + lr + r;
            Cf[coff + (long long)row * ldc + col] = acc[j][r];
        }
    }
}

// ---------- 5. ff2 GEMM (k-split 8) || memory update ----------
__global__ __launch_bounds__(256) void ff2_mem_k(
    const short* __restrict__ ff1_bf, const short* __restrict__ w2_bf,
    float* __restrict__ ff2_part,
    const float* __restrict__ memory, const float* __restrict__ momentum,
    const float* __restrict__ scores, const float* __restrict__ hbuf,
    const float* __restrict__ sur, const int* __restrict__ inv,
    float* __restrict__ mem_o, float* __restrict__ mom_o, float* __restrict__ sc_o)
{
    __shared__ short lds[5120];
    int j = blockIdx.x, t = threadIdx.x;
    if (j < 128) {
        int ks = j >> 4, r = j & 15;
        gemm_tile(lds, ff1_bf, 1024, w2_bf, 1024, ff2_part, 256,
                  (long long)ks * 65536, 128, ks * 128, r & 3, r >> 2);
        return;
    }
    int w = t >> 6, l = t & 63;
    int m = (j - 128) * 4 + w;
    int b = inv[m];
    long long o = (long long)m * 256 + l * 4;
    float4 xm = *(const float4*)(memory + o);
    float4 mo = *(const float4*)(momentum + o);
    if (b >= 0) {
        float4 hb = *(const float4*)(hbuf + (long long)b * 256 + l * 4);
        float4 nmom = {0.9f * mo.x + 0.1f * (hb.x - xm.x), 0.9f * mo.y + 0.1f * (hb.y - xm.y),
                       0.9f * mo.z + 0.1f * (hb.z - xm.z), 0.9f * mo.w + 0.1f * (hb.w - xm.w)};
        float4 nm4 = {xm.x + 0.1f * nmom.x, xm.y + 0.1f * nmom.y,
                      xm.z + 0.1f * nmom.z, xm.w + 0.1f * nmom.w};
        *(float4*)(mem_o + o) = nm4;
        *(float4*)(mom_o + o) = nmom;
        if (l == 0) sc_o[m] = sur[b];
    } else {
        *(float4*)(mem_o + o) = xm;
        *(float4*)(mom_o + o) = mo;
        if (l == 0) sc_o[m] = scores[m];
    }
}

// ---------- 6. final LayerNorm ----------
__global__ __launch_bounds__(256) void ln2_k(
    const float* __restrict__ ff2_part, const float* __restrict__ b2,
    const float* __restrict__ hbuf, const float* __restrict__ g2,
    const float* __restrict__ be2, float* __restrict__ out_main)
{
    int t = threadIdx.x, w = t >> 6, l = t & 63;
    int r = blockIdx.x * 4 + w;
    int c = l * 4;
    float4 x = *(const float4*)(b2 + c);
    float4 hv = *(const float4*)(hbuf + (long long)r * 256 + c);
    x.x += hv.x; x.y += hv.y; x.z += hv.z; x.w += hv.w;
    #pragma unroll
    for (int pp = 0; pp < 8; pp++) {
        float4 a = *(const float4*)(ff2_part + (long long)pp * 65536 + r * 256 + c);
        x.x += a.x; x.y += a.y; x.z += a.z; x.w += a.w;
    }
    float s = x.x + x.y + x.z + x.w;
    #pragma unroll
    for (int m = 32; m; m >>= 1) s += __shfl_xor(s, m, 64);
    float mean = s * (1.f / 256.f);
    float4 cv = {x.x - mean, x.y - mean, x.z - mean, x.w - mean};
    float ss = cv.x * cv.x + cv.y * cv.y + cv.z * cv.z + cv.w * cv.w;
    #pragma unroll
    for (int m = 32; m; m >>= 1) ss += __shfl_xor(ss, m, 64);
    float rstd = rsqrtf(ss * (1.f / 256.f) + 1e-5f);
    float4 gg = *(const float4*)(g2 + c);
    float4 bb = *(const float4*)(be2 + c);
    float4 y = {cv.x * rstd * gg.x + bb.x, cv.y * rstd * gg.y + bb.y,
                cv.z * rstd * gg.z + bb.z, cv.w * rstd * gg.w + bb.w};
    *(float4*)(out_main + (long long)r * 256 + c) = y;
}

extern "C" void kernel_launch(void* const* d_in, const int* in_sizes, int n_in,
                              void* d_out, int out_size, void* d_ws, size_t ws_size,
                              hipStream_t stream)
{
    const float* src      = (const float*)d_in[0];
    const float* memory   = (const float*)d_in[1];
    const float* momentum = (const float*)d_in[2];
    const float* scores   = (const float*)d_in[3];
    const float* ipw      = (const float*)d_in[4];
    const float* ipb      = (const float*)d_in[5];
    const float* out_w    = (const float*)d_in[6];
    const float* out_b    = (const float*)d_in[7];
    const float* w1       = (const float*)d_in[8];
    const float* b1       = (const float*)d_in[9];
    const float* w2       = (const float*)d_in[10];
    const float* b2       = (const float*)d_in[11];
    const float* g1       = (const float*)d_in[12];
    const float* be1      = (const float*)d_in[13];
    const float* g2       = (const float*)d_in[14];
    const float* be2      = (const float*)d_in[15];
    const int*   ptr      = (const int*)d_in[16];

    float* o = (float*)d_out;
    float* out_main = o;
    float* mem_o = o + 65536;
    float* mom_o = mem_o + 524288;
    float* sc_o  = mom_o + 524288;

    char* wp = (char*)d_ws;
    auto alloc = [&](size_t n) { void* q = (void*)wp; wp += (n + 255) & ~(size_t)255; return q; };
    short* qkv_bf   = (short*)alloc(393216);     // [256][768]
    short* k_bf     = (short*)alloc(1048576);    // [2048][256]
    short* vt_bf    = (short*)alloc(1048576);    // [256][2048]
    short* outw_bf  = (short*)alloc(131072);     // [256][256]
    short* w1_bf    = (short*)alloc(524288);     // [1024][256]
    short* w2_bf    = (short*)alloc(524288);     // [256][1024]
    short* ff1_bf   = (short*)alloc(524288);     // [256][1024]
    float* simdot   = (float*)alloc(2097152);    // [256][2048]
    float* pvpart   = (float*)alloc(2097152);    // [64 S][256 q][32 d]
    float* mpart    = (float*)alloc(65536);      // [64 S][256 q]
    float* lpart    = (float*)alloc(65536);
    float* attn_part= (float*)alloc(2097152);    // [8][256][256]
    float* ff2_part = (float*)alloc(2097152);    // [8][256][256]
    float* hbuf     = (float*)alloc(262144);     // [256][256] f32
    float* nx       = (float*)alloc(1024);
    float* nm       = (float*)alloc(8192);
    float* nm2      = (float*)alloc(8192);
    float* sur      = (float*)alloc(1024);
    int*   inv      = (int*)alloc(8192);

    // 1. projections + conversions + norms
    proj_k<<<612, 256, 0, stream>>>(src, memory, ipw, ipb, out_w, w1, w2,
        simdot, qkv_bf, k_bf, vt_bf, outw_bf, w1_bf, w2_bf, nx, nm, nm2);
    // 2. flash attention || surprise
    flash_sur_k<<<512, 256, 0, stream>>>(qkv_bf, k_bf, vt_bf, pvpart, mpart, lpart,
        simdot, nx, nm, nm2, sur);
    // 3. attn-out GEMM (inline combine) + accept scan
    attn_gemm_k<<<129, 256, 0, stream>>>(qkv_bf, mpart, lpart, pvpart, outw_bf,
        attn_part, sur, ptr, inv);
    // 4. ff1 GEMM (inline LN1; bx==0 writes hbuf)
    ff1_ln_k<<<dim3(16, 8), 256, 0, stream>>>(attn_part, out_b, src, g1, be1,
        w1_bf, b1, hbuf, ff1_bf);
    // 5. ff2 GEMM || memory update
    ff2_mem_k<<<640, 256, 0, stream>>>(ff1_bf, w2_bf, ff2_part,
        memory, momentum, scores, hbuf, sur, inv, mem_o, mom_o, sc_o);
    // 6. final LN
    ln2_k<<<64, 256, 0, stream>>>(ff2_part, b2, hbuf, g2, be2, out_main);
}